// Round 1
// baseline (5385.597 us; speedup 1.0000x reference)
//
#include <hip/hip_runtime.h>
#include <cstddef>

// ---------------------------------------------------------------------------
// DecoderWithAttention forward (show-attend-tell), fp32 reference-accurate.
// B=64, P=196 (14x14), ENC=2048, A=D=E=512, V=10000, T=21, Tdec=20.
// Round 1: correctness-first fp32 pipeline. Structure chosen so hot GEMMs
// (att1, fc, x@W_ih^T) can be swapped to bf16 MFMA in later rounds.
// ---------------------------------------------------------------------------

namespace {

constexpr int NB   = 64;
constexpr int NP   = 196;
constexpr int NE   = 2048;   // ENC
constexpr int NA   = 512;    // attention dim
constexpr int ND   = 512;    // decoder dim
constexpr int NEMB = 512;    // embedding dim
constexpr int NV   = 10000;  // vocab
constexpr int NT   = 21;
constexpr int NTD  = 20;     // Tdec

// ---- workspace layout (float offsets) ----
constexpr size_t OFF_ATT1  = 0;                                   // NB*NP*NA = 6,422,528
constexpr size_t OFF_MEAN  = OFF_ATT1 + (size_t)NB * NP * NA;     // NB*NE
constexpr size_t OFF_H     = OFF_MEAN + (size_t)NB * NE;          // NB*ND
constexpr size_t OFF_C     = OFF_H    + (size_t)NB * ND;
constexpr size_t OFF_HNEW  = OFF_C    + (size_t)NB * ND;
constexpr size_t OFF_ATT2  = OFF_HNEW + (size_t)NB * ND;          // NB*NA
constexpr size_t OFF_GATE  = OFF_ATT2 + (size_t)NB * NA;          // NB*NE
constexpr size_t OFF_HH    = OFF_GATE + (size_t)NB * NE;          // NB*2048
constexpr size_t OFF_ALPHA = OFF_HH   + (size_t)NB * 2048;        // NB*NP
constexpr size_t OFF_AWE   = OFF_ALPHA+ (size_t)NB * NP;          // NB*NE
constexpr size_t OFF_X     = OFF_AWE  + (size_t)NB * NE;          // NB*2560
constexpr size_t OFF_PART  = OFF_X    + (size_t)NB * 2560;        // 4*NB*2048
constexpr size_t OFF_INT   = OFF_PART + 4 * (size_t)NB * 2048;    // ints below
// ints (on top of float base): perm[64], declen[64], caps_sorted[64*21]

__device__ __forceinline__ float sigmoidf(float x) { return 1.0f / (1.0f + expf(-x)); }

// ---------------------------------------------------------------------------
// K1: stable descending argsort of clipped caption lengths (B=64), plus
//     gathered caps / dec_len / sort_ind outputs.
// ---------------------------------------------------------------------------
__global__ void k_sort(const int* __restrict__ cap_len, const int* __restrict__ caps,
                       int* __restrict__ perm, int* __restrict__ declen,
                       int* __restrict__ caps_sorted,
                       float* __restrict__ out_caps, float* __restrict__ out_declen,
                       float* __restrict__ out_sortind) {
  __shared__ int cl[NB];
  __shared__ int pr[NB];
  const int i = threadIdx.x;  // 64 threads
  int c = cap_len[i];
  if (c < 1) c = 1;
  cl[i] = c;
  __syncthreads();
  int rank = 0;
  for (int j = 0; j < NB; ++j) {
    const int cj = cl[j];
    if (cj > c || (cj == c && j < i)) rank++;
  }
  pr[rank] = i;
  __syncthreads();
  const int src = pr[i];
  perm[i] = src;
  const int dl = cl[src] - 1;
  declen[i] = dl;
  out_declen[i] = (float)dl;
  out_sortind[i] = (float)src;
  for (int j = 0; j < NT; ++j) {
    const int v = caps[src * NT + j];
    caps_sorted[i * NT + j] = v;
    out_caps[i * NT + j] = (float)v;
  }
}

// ---------------------------------------------------------------------------
// K2: mean over P of sorted encoder rows -> mean_enc (B x 2048)
// ---------------------------------------------------------------------------
__global__ __launch_bounds__(256) void k_mean(const float* __restrict__ enc,
                                              const int* __restrict__ perm,
                                              float* __restrict__ mean_enc) {
  const int b = blockIdx.x;
  const float* base = enc + (size_t)perm[b] * NP * NE;
  for (int c = threadIdx.x; c < NE; c += 256) {
    float acc = 0.0f;
    for (int p = 0; p < NP; ++p) acc += base[(size_t)p * NE + c];
    mean_enc[(size_t)b * NE + c] = acc * (1.0f / (float)NP);
  }
}

// ---------------------------------------------------------------------------
// K3: h0/c0 = tanh(mean_enc @ W + b). grid (8, 2): y=0 -> h, y=1 -> c.
//     M=64, K=2048, N=512, W layout K-major (k*512+n).
// ---------------------------------------------------------------------------
__global__ __launch_bounds__(256) void k_init_hc(const float* __restrict__ mean_enc,
                                                 const float* __restrict__ Wh,
                                                 const float* __restrict__ bh,
                                                 const float* __restrict__ Wc,
                                                 const float* __restrict__ bc,
                                                 float* __restrict__ h, float* __restrict__ c) {
  __shared__ float Xs[16][65];
  __shared__ float Ws[16][65];
  const float* W    = blockIdx.y ? Wc : Wh;
  const float* bias = blockIdx.y ? bc : bh;
  float* out        = blockIdx.y ? c : h;
  const int n0 = blockIdx.x * 64;
  const int tid = threadIdx.x, tx = tid & 15, ty = tid >> 4;
  float acc[4][4] = {};
  for (int k0 = 0; k0 < 2048; k0 += 16) {
    {
      const int kk = tid & 15, bq = tid >> 4;
#pragma unroll
      for (int u = 0; u < 4; ++u) {
        const int bb = bq + 16 * u;
        Xs[kk][bb] = mean_enc[(size_t)bb * NE + k0 + kk];
      }
    }
    {
      const int nn = tid & 63, kq = tid >> 6;
#pragma unroll
      for (int u = 0; u < 4; ++u) {
        const int kk = kq + 4 * u;
        Ws[kk][nn] = W[(size_t)(k0 + kk) * ND + n0 + nn];
      }
    }
    __syncthreads();
#pragma unroll
    for (int kk = 0; kk < 16; ++kk) {
      const float a0 = Xs[kk][ty], a1 = Xs[kk][ty + 16], a2 = Xs[kk][ty + 32], a3 = Xs[kk][ty + 48];
      const float w0 = Ws[kk][tx], w1 = Ws[kk][tx + 16], w2 = Ws[kk][tx + 32], w3 = Ws[kk][tx + 48];
      acc[0][0] += a0 * w0; acc[0][1] += a0 * w1; acc[0][2] += a0 * w2; acc[0][3] += a0 * w3;
      acc[1][0] += a1 * w0; acc[1][1] += a1 * w1; acc[1][2] += a1 * w2; acc[1][3] += a1 * w3;
      acc[2][0] += a2 * w0; acc[2][1] += a2 * w1; acc[2][2] += a2 * w2; acc[2][3] += a2 * w3;
      acc[3][0] += a3 * w0; acc[3][1] += a3 * w1; acc[3][2] += a3 * w2; acc[3][3] += a3 * w3;
    }
    __syncthreads();
  }
#pragma unroll
  for (int i = 0; i < 4; ++i) {
    const int b = ty + 16 * i;
#pragma unroll
    for (int j = 0; j < 4; ++j) {
      const int n = n0 + tx + 16 * j;
      out[(size_t)b * ND + n] = tanhf(acc[i][j] + bias[n]);
    }
  }
}

// ---------------------------------------------------------------------------
// K4: att1 = enc_sorted @ enc_att_W + b. M=12544 (196 row-tiles of 64),
//     N=512 (8 col-tiles), K=2048. Rows gathered through perm.
// ---------------------------------------------------------------------------
__global__ __launch_bounds__(256) void k_att1(const float* __restrict__ enc,
                                              const int* __restrict__ perm,
                                              const float* __restrict__ W,
                                              const float* __restrict__ bias,
                                              float* __restrict__ att1) {
  __shared__ float Xs[16][65];
  __shared__ float Ws[16][65];
  __shared__ int rowoff[64];
  const int by = blockIdx.y;
  const int n0 = blockIdx.x * 64;
  const int tid = threadIdx.x, tx = tid & 15, ty = tid >> 4;
  if (tid < 64) {
    const int r = by * 64 + tid;
    const int bs = r / NP, p = r % NP;
    rowoff[tid] = (perm[bs] * NP + p) * NE;
  }
  __syncthreads();
  float acc[4][4] = {};
  for (int k0 = 0; k0 < 2048; k0 += 16) {
    {
      const int kk = tid & 15, bq = tid >> 4;
#pragma unroll
      for (int u = 0; u < 4; ++u) {
        const int bb = bq + 16 * u;
        Xs[kk][bb] = enc[(size_t)rowoff[bb] + k0 + kk];
      }
    }
    {
      const int nn = tid & 63, kq = tid >> 6;
#pragma unroll
      for (int u = 0; u < 4; ++u) {
        const int kk = kq + 4 * u;
        Ws[kk][nn] = W[(size_t)(k0 + kk) * NA + n0 + nn];
      }
    }
    __syncthreads();
#pragma unroll
    for (int kk = 0; kk < 16; ++kk) {
      const float a0 = Xs[kk][ty], a1 = Xs[kk][ty + 16], a2 = Xs[kk][ty + 32], a3 = Xs[kk][ty + 48];
      const float w0 = Ws[kk][tx], w1 = Ws[kk][tx + 16], w2 = Ws[kk][tx + 32], w3 = Ws[kk][tx + 48];
      acc[0][0] += a0 * w0; acc[0][1] += a0 * w1; acc[0][2] += a0 * w2; acc[0][3] += a0 * w3;
      acc[1][0] += a1 * w0; acc[1][1] += a1 * w1; acc[1][2] += a1 * w2; acc[1][3] += a1 * w3;
      acc[2][0] += a2 * w0; acc[2][1] += a2 * w1; acc[2][2] += a2 * w2; acc[2][3] += a2 * w3;
      acc[3][0] += a3 * w0; acc[3][1] += a3 * w1; acc[3][2] += a3 * w2; acc[3][3] += a3 * w3;
    }
    __syncthreads();
  }
#pragma unroll
  for (int i = 0; i < 4; ++i) {
    const int r = by * 64 + ty + 16 * i;
#pragma unroll
    for (int j = 0; j < 4; ++j) {
      const int n = n0 + tx + 16 * j;
      att1[(size_t)r * NA + n] = acc[i][j] + bias[n];
    }
  }
}

// ---------------------------------------------------------------------------
// K5 (per step): fused h-GEMM. N = 4608 logical columns:
//   [0,512)     att2   = h @ dec_att_W + dec_att_b
//   [512,2560)  gate   = sigmoid(h @ f_beta_W + f_beta_b)
//   [2560,4608) hh     = h @ W_hh^T + b_hh + b_ih
// M=64, K=512. 72 blocks.
// ---------------------------------------------------------------------------
__global__ __launch_bounds__(256) void k_hgemm(const float* __restrict__ h,
                                               const float* __restrict__ dec_att_W,
                                               const float* __restrict__ dec_att_b,
                                               const float* __restrict__ f_beta_W,
                                               const float* __restrict__ f_beta_b,
                                               const float* __restrict__ W_hh,
                                               const float* __restrict__ b_hh,
                                               const float* __restrict__ b_ih,
                                               float* __restrict__ att2,
                                               float* __restrict__ gate,
                                               float* __restrict__ hh) {
  __shared__ float Xs[16][65];
  __shared__ float Ws[16][65];
  const int n0g = blockIdx.x * 64;
  const int tid = threadIdx.x, tx = tid & 15, ty = tid >> 4;
  int mode, wld, ncol0;
  const float* W;
  if (n0g < 512)       { mode = 0; W = dec_att_W; wld = 512;  ncol0 = n0g; }
  else if (n0g < 2560) { mode = 1; W = f_beta_W;  wld = 2048; ncol0 = n0g - 512; }
  else                 { mode = 2; W = W_hh;      wld = 512;  ncol0 = n0g - 2560; }
  float acc[4][4] = {};
  for (int k0 = 0; k0 < 512; k0 += 16) {
    {
      const int kk = tid & 15, bq = tid >> 4;
#pragma unroll
      for (int u = 0; u < 4; ++u) {
        const int bb = bq + 16 * u;
        Xs[kk][bb] = h[(size_t)bb * ND + k0 + kk];
      }
    }
    if (mode == 2) {  // N-major weight: W[n*wld + k]
      const int kk = tid & 15, nq = tid >> 4;
#pragma unroll
      for (int u = 0; u < 4; ++u) {
        const int nn = nq + 16 * u;
        Ws[kk][nn] = W[(size_t)(ncol0 + nn) * wld + k0 + kk];
      }
    } else {          // K-major weight: W[k*wld + n]
      const int nn = tid & 63, kq = tid >> 6;
#pragma unroll
      for (int u = 0; u < 4; ++u) {
        const int kk = kq + 4 * u;
        Ws[kk][nn] = W[(size_t)(k0 + kk) * wld + ncol0 + nn];
      }
    }
    __syncthreads();
#pragma unroll
    for (int kk = 0; kk < 16; ++kk) {
      const float a0 = Xs[kk][ty], a1 = Xs[kk][ty + 16], a2 = Xs[kk][ty + 32], a3 = Xs[kk][ty + 48];
      const float w0 = Ws[kk][tx], w1 = Ws[kk][tx + 16], w2 = Ws[kk][tx + 32], w3 = Ws[kk][tx + 48];
      acc[0][0] += a0 * w0; acc[0][1] += a0 * w1; acc[0][2] += a0 * w2; acc[0][3] += a0 * w3;
      acc[1][0] += a1 * w0; acc[1][1] += a1 * w1; acc[1][2] += a1 * w2; acc[1][3] += a1 * w3;
      acc[2][0] += a2 * w0; acc[2][1] += a2 * w1; acc[2][2] += a2 * w2; acc[2][3] += a2 * w3;
      acc[3][0] += a3 * w0; acc[3][1] += a3 * w1; acc[3][2] += a3 * w2; acc[3][3] += a3 * w3;
    }
    __syncthreads();
  }
#pragma unroll
  for (int i = 0; i < 4; ++i) {
    const int b = ty + 16 * i;
#pragma unroll
    for (int j = 0; j < 4; ++j) {
      const int col = ncol0 + tx + 16 * j;
      const float v = acc[i][j];
      if (mode == 0)      att2[(size_t)b * NA + col] = v + dec_att_b[col];
      else if (mode == 1) gate[(size_t)b * NE + col] = sigmoidf(v + f_beta_b[col]);
      else                hh[(size_t)b * 2048 + col] = v + b_hh[col] + b_ih[col];
    }
  }
}

// ---------------------------------------------------------------------------
// K6 (per step): attention logits + softmax. One block per b.
//   e[p] = sum_a relu(att1[b,p,a] + att2[b,a]) * full_att_W[a]
//   alpha = softmax(e); write alpha to ws and masked alphas output.
// ---------------------------------------------------------------------------
__global__ __launch_bounds__(256) void k_attn(const float* __restrict__ att1,
                                              const float* __restrict__ att2,
                                              const float* __restrict__ fullW,
                                              const int* __restrict__ declen, int t,
                                              float* __restrict__ alpha_ws,
                                              float* __restrict__ out_alphas) {
  const int b = blockIdx.x;
  __shared__ float a2s[NA];
  __shared__ float fws[NA];
  __shared__ float e[NP + 12];
  __shared__ float sred[256];
  const int tid = threadIdx.x;
  a2s[tid]       = att2[(size_t)b * NA + tid];
  a2s[tid + 256] = att2[(size_t)b * NA + tid + 256];
  fws[tid]       = fullW[tid];
  fws[tid + 256] = fullW[tid + 256];
  __syncthreads();
  const int wave = tid >> 6, lane = tid & 63;
  for (int p = wave; p < NP; p += 4) {
    const float* row = att1 + (size_t)(b * NP + p) * NA;
    float acc = 0.0f;
#pragma unroll
    for (int a0 = 0; a0 < NA; a0 += 64) {
      const int a = a0 + lane;
      const float v = row[a] + a2s[a];
      acc += fmaxf(v, 0.0f) * fws[a];
    }
#pragma unroll
    for (int off = 32; off > 0; off >>= 1) acc += __shfl_down(acc, off, 64);
    if (lane == 0) e[p] = acc;
  }
  __syncthreads();
  // softmax over 196
  sred[tid] = (tid < NP) ? e[tid] : -INFINITY;
  __syncthreads();
  for (int s = 128; s > 0; s >>= 1) {
    if (tid < s) sred[tid] = fmaxf(sred[tid], sred[tid + s]);
    __syncthreads();
  }
  const float m = sred[0];
  __syncthreads();
  const float ex = (tid < NP) ? expf(e[tid] - m) : 0.0f;
  sred[tid] = ex;
  __syncthreads();
  for (int s = 128; s > 0; s >>= 1) {
    if (tid < s) sred[tid] += sred[tid + s];
    __syncthreads();
  }
  const float inv = 1.0f / sred[0];
  if (tid < NP) {
    const float al = ex * inv;
    alpha_ws[(size_t)b * NP + tid] = al;
    const bool act = t < declen[b];
    out_alphas[((size_t)b * NTD + t) * NP + tid] = act ? al : 0.0f;
  }
}

// ---------------------------------------------------------------------------
// K7 (per step): awe[b,c] = gate[b,c] * sum_p alpha[b,p] * enc[b,p,c].
// grid 64*8 blocks; block (b, slice of 256 channels).
// ---------------------------------------------------------------------------
__global__ __launch_bounds__(256) void k_awe(const float* __restrict__ enc,
                                             const int* __restrict__ perm,
                                             const float* __restrict__ alpha_ws,
                                             const float* __restrict__ gate,
                                             float* __restrict__ awe) {
  const int b = blockIdx.x >> 3;
  const int s = blockIdx.x & 7;
  __shared__ float al[NP];
  const int tid = threadIdx.x;
  if (tid < NP) al[tid] = alpha_ws[(size_t)b * NP + tid];
  __syncthreads();
  const int c = s * 256 + tid;
  const float* base = enc + (size_t)perm[b] * NP * NE + c;
  float acc = 0.0f;
#pragma unroll 4
  for (int p = 0; p < NP; ++p) acc += al[p] * base[(size_t)p * NE];
  awe[(size_t)b * NE + c] = acc * gate[(size_t)b * NE + c];
}

// ---------------------------------------------------------------------------
// K8 (per step): x = [emb[caps[b,t]] | awe[b]]  (64 x 2560)
// ---------------------------------------------------------------------------
__global__ __launch_bounds__(256) void k_buildx(const float* __restrict__ emb,
                                                const int* __restrict__ caps_sorted,
                                                const float* __restrict__ awe, int t,
                                                float* __restrict__ x) {
  const int b = blockIdx.x;
  const int cap = caps_sorted[b * NT + t];
  for (int k = threadIdx.x; k < 2560; k += 256) {
    x[(size_t)b * 2560 + k] =
        (k < NEMB) ? emb[(size_t)cap * NEMB + k] : awe[(size_t)b * NE + (k - NEMB)];
  }
}

// ---------------------------------------------------------------------------
// K9 (per step): x @ W_ih^T, K-split into 4 partials of 640.
// M=64, N=2048, W_ih is N-major (n*2560 + k). grid (32, 4).
// ---------------------------------------------------------------------------
__global__ __launch_bounds__(256) void k_xgemm(const float* __restrict__ x,
                                               const float* __restrict__ W_ih,
                                               float* __restrict__ part) {
  __shared__ float Xs[16][65];
  __shared__ float Ws[16][65];
  const int n0 = blockIdx.x * 64;
  const int ks = blockIdx.y;
  const int kbase = ks * 640;
  const int tid = threadIdx.x, tx = tid & 15, ty = tid >> 4;
  float acc[4][4] = {};
  for (int k0 = kbase; k0 < kbase + 640; k0 += 16) {
    {
      const int kk = tid & 15, bq = tid >> 4;
#pragma unroll
      for (int u = 0; u < 4; ++u) {
        const int bb = bq + 16 * u;
        Xs[kk][bb] = x[(size_t)bb * 2560 + k0 + kk];
      }
    }
    {
      const int kk = tid & 15, nq = tid >> 4;
#pragma unroll
      for (int u = 0; u < 4; ++u) {
        const int nn = nq + 16 * u;
        Ws[kk][nn] = W_ih[(size_t)(n0 + nn) * 2560 + k0 + kk];
      }
    }
    __syncthreads();
#pragma unroll
    for (int kk = 0; kk < 16; ++kk) {
      const float a0 = Xs[kk][ty], a1 = Xs[kk][ty + 16], a2 = Xs[kk][ty + 32], a3 = Xs[kk][ty + 48];
      const float w0 = Ws[kk][tx], w1 = Ws[kk][tx + 16], w2 = Ws[kk][tx + 32], w3 = Ws[kk][tx + 48];
      acc[0][0] += a0 * w0; acc[0][1] += a0 * w1; acc[0][2] += a0 * w2; acc[0][3] += a0 * w3;
      acc[1][0] += a1 * w0; acc[1][1] += a1 * w1; acc[1][2] += a1 * w2; acc[1][3] += a1 * w3;
      acc[2][0] += a2 * w0; acc[2][1] += a2 * w1; acc[2][2] += a2 * w2; acc[2][3] += a2 * w3;
      acc[3][0] += a3 * w0; acc[3][1] += a3 * w1; acc[3][2] += a3 * w2; acc[3][3] += a3 * w3;
    }
    __syncthreads();
  }
#pragma unroll
  for (int i = 0; i < 4; ++i) {
    const int b = ty + 16 * i;
#pragma unroll
    for (int j = 0; j < 4; ++j) {
      const int n = n0 + tx + 16 * j;
      part[(size_t)ks * NB * 2048 + (size_t)b * 2048 + n] = acc[i][j];
    }
  }
}

// ---------------------------------------------------------------------------
// K10 (per step): LSTM cell. gates = sum(partials) + hh (hh already holds
// b_ih + b_hh + h@W_hh^T). Updates h,c where active; hnew always written.
// ---------------------------------------------------------------------------
__global__ __launch_bounds__(256) void k_lstm(const float* __restrict__ part,
                                              const float* __restrict__ hh,
                                              const int* __restrict__ declen, int t,
                                              float* __restrict__ h, float* __restrict__ c,
                                              float* __restrict__ hnew) {
  const int idx = blockIdx.x * 256 + threadIdx.x;  // 0..32767
  const int b = idx >> 9, d = idx & 511;
  const size_t rb = (size_t)b * 2048;
  float g[4];
#pragma unroll
  for (int q = 0; q < 4; ++q) {
    const int col = q * 512 + d;
    float v = hh[rb + col];
    v += part[0 * (size_t)NB * 2048 + rb + col];
    v += part[1 * (size_t)NB * 2048 + rb + col];
    v += part[2 * (size_t)NB * 2048 + rb + col];
    v += part[3 * (size_t)NB * 2048 + rb + col];
    g[q] = v;
  }
  const float cold = c[idx];
  const float cn = sigmoidf(g[1]) * cold + sigmoidf(g[0]) * tanhf(g[2]);
  const float hn = sigmoidf(g[3]) * tanhf(cn);
  hnew[idx] = hn;
  if (t < declen[b]) {
    h[idx] = hn;
    c[idx] = cn;
  }
}

// ---------------------------------------------------------------------------
// K11 (per step): preds = hnew @ fc_W + fc_b, masked write to predictions.
// M=64, K=512, N=10000 (157 col-tiles, guarded). fc_W K-major (k*10000+n).
// ---------------------------------------------------------------------------
__global__ __launch_bounds__(256) void k_fc(const float* __restrict__ hnew,
                                            const float* __restrict__ fcW,
                                            const float* __restrict__ fcb,
                                            const int* __restrict__ declen, int t,
                                            float* __restrict__ out_pred) {
  __shared__ float Xs[16][65];
  __shared__ float Ws[16][65];
  const int n0 = blockIdx.x * 64;
  const int tid = threadIdx.x, tx = tid & 15, ty = tid >> 4;
  float acc[4][4] = {};
  for (int k0 = 0; k0 < 512; k0 += 16) {
    {
      const int kk = tid & 15, bq = tid >> 4;
#pragma unroll
      for (int u = 0; u < 4; ++u) {
        const int bb = bq + 16 * u;
        Xs[kk][bb] = hnew[(size_t)bb * ND + k0 + kk];
      }
    }
    {
      const int nn = tid & 63, kq = tid >> 6;
#pragma unroll
      for (int u = 0; u < 4; ++u) {
        const int kk = kq + 4 * u;
        const int n = n0 + nn;
        Ws[kk][nn] = (n < NV) ? fcW[(size_t)(k0 + kk) * NV + n] : 0.0f;
      }
    }
    __syncthreads();
#pragma unroll
    for (int kk = 0; kk < 16; ++kk) {
      const float a0 = Xs[kk][ty], a1 = Xs[kk][ty + 16], a2 = Xs[kk][ty + 32], a3 = Xs[kk][ty + 48];
      const float w0 = Ws[kk][tx], w1 = Ws[kk][tx + 16], w2 = Ws[kk][tx + 32], w3 = Ws[kk][tx + 48];
      acc[0][0] += a0 * w0; acc[0][1] += a0 * w1; acc[0][2] += a0 * w2; acc[0][3] += a0 * w3;
      acc[1][0] += a1 * w0; acc[1][1] += a1 * w1; acc[1][2] += a1 * w2; acc[1][3] += a1 * w3;
      acc[2][0] += a2 * w0; acc[2][1] += a2 * w1; acc[2][2] += a2 * w2; acc[2][3] += a2 * w3;
      acc[3][0] += a3 * w0; acc[3][1] += a3 * w1; acc[3][2] += a3 * w2; acc[3][3] += a3 * w3;
    }
    __syncthreads();
  }
#pragma unroll
  for (int i = 0; i < 4; ++i) {
    const int b = ty + 16 * i;
    const bool act = t < declen[b];
#pragma unroll
    for (int j = 0; j < 4; ++j) {
      const int n = n0 + tx + 16 * j;
      if (n < NV) {
        out_pred[((size_t)b * NTD + t) * NV + n] = act ? (acc[i][j] + fcb[n]) : 0.0f;
      }
    }
  }
}

}  // namespace

extern "C" void kernel_launch(void* const* d_in, const int* in_sizes, int n_in,
                              void* d_out, int out_size, void* d_ws, size_t ws_size,
                              hipStream_t stream) {
  const float* enc        = (const float*)d_in[0];
  const int*   caps       = (const int*)d_in[1];
  const int*   caplen     = (const int*)d_in[2];
  const float* emb        = (const float*)d_in[3];
  const float* enc_att_W  = (const float*)d_in[4];
  const float* enc_att_b  = (const float*)d_in[5];
  const float* dec_att_W  = (const float*)d_in[6];
  const float* dec_att_b  = (const float*)d_in[7];
  const float* full_att_W = (const float*)d_in[8];
  // d_in[9] full_att_b: shift-invariant under softmax, unused.
  const float* init_h_W   = (const float*)d_in[10];
  const float* init_h_b   = (const float*)d_in[11];
  const float* init_c_W   = (const float*)d_in[12];
  const float* init_c_b   = (const float*)d_in[13];
  const float* f_beta_W   = (const float*)d_in[14];
  const float* f_beta_b   = (const float*)d_in[15];
  const float* W_ih       = (const float*)d_in[16];
  const float* b_ih       = (const float*)d_in[17];
  const float* W_hh       = (const float*)d_in[18];
  const float* b_hh       = (const float*)d_in[19];
  const float* fc_W       = (const float*)d_in[20];
  const float* fc_b       = (const float*)d_in[21];

  float* ws = (float*)d_ws;
  float* att1   = ws + OFF_ATT1;
  float* mean_e = ws + OFF_MEAN;
  float* h      = ws + OFF_H;
  float* c      = ws + OFF_C;
  float* hnew   = ws + OFF_HNEW;
  float* att2   = ws + OFF_ATT2;
  float* gate   = ws + OFF_GATE;
  float* hh     = ws + OFF_HH;
  float* alpha  = ws + OFF_ALPHA;
  float* awe    = ws + OFF_AWE;
  float* x      = ws + OFF_X;
  float* part   = ws + OFF_PART;
  int* wsi      = (int*)(ws + OFF_INT);
  int* perm     = wsi;
  int* declen   = wsi + 64;
  int* caps_s   = wsi + 128;

  float* out         = (float*)d_out;
  float* out_pred    = out;                                     // B*Tdec*V
  float* out_caps    = out_pred + (size_t)NB * NTD * NV;        // B*T
  float* out_declen  = out_caps + (size_t)NB * NT;              // B
  float* out_alphas  = out_declen + NB;                         // B*Tdec*P
  float* out_sortind = out_alphas + (size_t)NB * NTD * NP;      // B

  k_sort<<<1, 64, 0, stream>>>(caplen, caps, perm, declen, caps_s,
                               out_caps, out_declen, out_sortind);
  k_mean<<<NB, 256, 0, stream>>>(enc, perm, mean_e);
  k_init_hc<<<dim3(8, 2), 256, 0, stream>>>(mean_e, init_h_W, init_h_b,
                                            init_c_W, init_c_b, h, c);
  k_att1<<<dim3(8, NP), 256, 0, stream>>>(enc, perm, enc_att_W, enc_att_b, att1);

  for (int t = 0; t < NTD; ++t) {
    k_hgemm<<<72, 256, 0, stream>>>(h, dec_att_W, dec_att_b, f_beta_W, f_beta_b,
                                    W_hh, b_hh, b_ih, att2, gate, hh);
    k_attn<<<NB, 256, 0, stream>>>(att1, att2, full_att_W, declen, t,
                                   alpha, out_alphas);
    k_awe<<<NB * 8, 256, 0, stream>>>(enc, perm, alpha, gate, awe);
    k_buildx<<<NB, 256, 0, stream>>>(emb, caps_s, awe, t, x);
    k_xgemm<<<dim3(32, 4), 256, 0, stream>>>(x, W_ih, part);
    k_lstm<<<128, 256, 0, stream>>>(part, hh, declen, t, h, c, hnew);
    k_fc<<<157, 256, 0, stream>>>(hnew, fc_W, fc_b, declen, t, out_pred);
  }
}

// Round 2
// 2969.050 us; speedup vs baseline: 1.8139x; 1.8139x over previous
//
#include <hip/hip_runtime.h>
#include <cstddef>

// ---------------------------------------------------------------------------
// DecoderWithAttention forward — Round 2: f16 MFMA pipeline.
// B=64, P=196, ENC=2048, A=D=E=512, V=10000, Tdec=20.
// All GEMMs on v_mfma_f32_16x16x32_f16 (fp32 accumulate). LSTM cell fused
// into the x@W_ih^T epilogue. Weights pre-transposed/converted to f16 once
// per call. enc optionally cached as sorted f16 when ws_size allows.
// ---------------------------------------------------------------------------

namespace {

typedef _Float16 f16;
typedef f16 f16x8 __attribute__((ext_vector_type(8)));
typedef f16 f16x2 __attribute__((ext_vector_type(2)));
typedef float f32x4 __attribute__((ext_vector_type(4)));

constexpr int NB = 64, NP = 196, NE = 2048, NA = 512, ND = 512, NV = 10000;
constexpr int NT_CAP = 21, NTD = 20;
constexpr int LDT = 40;  // LDS tile row stride in f16 (80 B, 16B-aligned, conflict-light)

// ---- workspace byte offsets (all 256-aligned) ----
constexpr size_t OFF_ATT1   = 0;          // f16 [12544][512]        12,845,056
constexpr size_t OFF_EAW    = 12845056;   // f16 [512][2048] enc_att^T
constexpr size_t OFF_DAW    = 14942208;   // f16 [512][512]  dec_att^T
constexpr size_t OFF_FBW    = 15466496;   // f16 [2048][512] f_beta^T
constexpr size_t OFF_IHW    = 17563648;   // f16 [512][2048] init_h^T
constexpr size_t OFF_ICW    = 19660800;   // f16 [512][2048] init_c^T
constexpr size_t OFF_MEAN   = 21757952;   // f32 [64][2048]
constexpr size_t OFF_MEAN16 = 22282240;   // f16 [64][2048]
constexpr size_t OFF_H16    = 22544384;   // f16 [64][512]
constexpr size_t OFF_HNEW16 = 22609920;   // f16 [64][512]
constexpr size_t OFF_C      = 22675456;   // f32 [64][512]
constexpr size_t OFF_ATT2   = 22806528;   // f32 [64][512]
constexpr size_t OFF_GATE   = 22937600;   // f32 [64][2048]
constexpr size_t OFF_HH     = 23461888;   // f32 [64][2048]
constexpr size_t OFF_ALPHA  = 23986176;   // f32 [64][196]
constexpr size_t OFF_X16    = 24036352;   // f16 [64][2560]
constexpr size_t OFF_INT    = 24364032;   // perm[64], declen[64], caps_s[64*21]
constexpr size_t OFF_ENC16  = 24369920;   // f16 [64][196][2048] (optional)
constexpr size_t FULL_BYTES = 75750144;

__device__ __forceinline__ float sigmoidf_(float x) { return 1.0f / (1.0f + expf(-x)); }

// stage 8 f16 from f16 source row into LDS (16 B per thread)
__device__ __forceinline__ void stage16(const f16* __restrict__ src, int lda, int k0,
                                        f16* __restrict__ lds, int tid) {
  const int row = tid >> 2, seg = tid & 3;
  *(f16x8*)&lds[row * LDT + seg * 8] =
      *(const f16x8*)&src[(size_t)row * lda + k0 + seg * 8];
}

// convert 8 consecutive fp32 -> 8 f16 at dst
__device__ __forceinline__ void cvt8(const float* __restrict__ p, f16* __restrict__ dst) {
  const float4 a = *(const float4*)p;
  const float4 b = *(const float4*)(p + 4);
  f16x8 v;
  v[0] = (f16)a.x; v[1] = (f16)a.y; v[2] = (f16)a.z; v[3] = (f16)a.w;
  v[4] = (f16)b.x; v[5] = (f16)b.y; v[6] = (f16)b.z; v[7] = (f16)b.w;
  *(f16x8*)dst = v;
}

template <int NT>
__device__ __forceinline__ void mfma_step(const f16* __restrict__ lA, const f16* __restrict__ lB,
                                          int wv, int col, int quad, f32x4* acc) {
  const f16x8 a = *(const f16x8*)&lA[(wv * 16 + col) * LDT + quad * 8];
#pragma unroll
  for (int ns = 0; ns < NT; ++ns) {
    const f16x8 b = *(const f16x8*)&lB[(ns * 16 + col) * LDT + quad * 8];
    acc[ns] = __builtin_amdgcn_mfma_f32_16x16x32_f16(a, b, acc[ns], 0, 0, 0);
  }
}

// ---------------------------------------------------------------------------
// K1: stable descending argsort of clipped caption lengths + gathered outputs.
// ---------------------------------------------------------------------------
__global__ void k_sort(const int* __restrict__ cap_len, const int* __restrict__ caps,
                       int* __restrict__ perm, int* __restrict__ declen,
                       int* __restrict__ caps_sorted,
                       float* __restrict__ out_caps, float* __restrict__ out_declen,
                       float* __restrict__ out_sortind) {
  __shared__ int cl[NB];
  __shared__ int pr[NB];
  const int i = threadIdx.x;
  int c = cap_len[i];
  if (c < 1) c = 1;
  cl[i] = c;
  __syncthreads();
  int rank = 0;
  for (int j = 0; j < NB; ++j) {
    const int cj = cl[j];
    if (cj > c || (cj == c && j < i)) rank++;
  }
  pr[rank] = i;
  __syncthreads();
  const int src = pr[i];
  perm[i] = src;
  const int dl = cl[src] - 1;
  declen[i] = dl;
  out_declen[i] = (float)dl;
  out_sortind[i] = (float)src;
  for (int j = 0; j < NT_CAP; ++j) {
    const int v = caps[src * NT_CAP + j];
    caps_sorted[i * NT_CAP + j] = v;
    out_caps[i * NT_CAP + j] = (float)v;
  }
}

// ---------------------------------------------------------------------------
// K2: transpose-convert fp32 [K][N] (K-major) -> f16 [N][K]. 32x32 tiles.
// ---------------------------------------------------------------------------
__global__ __launch_bounds__(256) void k_tconv(const float* __restrict__ src,
                                               f16* __restrict__ dst, int K, int N) {
  __shared__ float tile[32][33];
  const int n0 = blockIdx.x * 32, k0 = blockIdx.y * 32;
  const int tid = threadIdx.x;
  const int a = tid & 31, q = tid >> 5;  // q: 0..7
#pragma unroll
  for (int r = 0; r < 4; ++r) {
    const int kl = q * 4 + r;
    tile[a][kl] = src[(size_t)(k0 + kl) * N + n0 + a];
  }
  __syncthreads();
#pragma unroll
  for (int r = 0; r < 4; ++r) {
    const int nl = q * 4 + r;
    dst[(size_t)(n0 + nl) * K + k0 + a] = (f16)tile[nl][a];
  }
}

// ---------------------------------------------------------------------------
// K3: mean over P of sorted encoder rows -> mean (f32) + mean16 (f16).
// grid (4, 64): 512-channel slices per b, 2 channels/thread.
// ---------------------------------------------------------------------------
__global__ __launch_bounds__(256) void k_mean(const float* __restrict__ enc,
                                              const int* __restrict__ perm,
                                              float* __restrict__ mean,
                                              f16* __restrict__ mean16) {
  const int b = blockIdx.y;
  const int c0 = blockIdx.x * 512 + threadIdx.x * 2;
  const float* base = enc + (size_t)perm[b] * NP * NE + c0;
  float a0 = 0.0f, a1 = 0.0f;
  for (int p = 0; p < NP; ++p) {
    const float2 v = *(const float2*)&base[(size_t)p * NE];
    a0 += v.x; a1 += v.y;
  }
  a0 *= (1.0f / (float)NP); a1 *= (1.0f / (float)NP);
  mean[(size_t)b * NE + c0] = a0;  mean[(size_t)b * NE + c0 + 1] = a1;
  mean16[(size_t)b * NE + c0] = (f16)a0;  mean16[(size_t)b * NE + c0 + 1] = (f16)a1;
}

// ---------------------------------------------------------------------------
// K4 (FULL only): enc16[b][p][c] = f16(enc[perm[b]][p][c]). grid (196, 64).
// ---------------------------------------------------------------------------
__global__ __launch_bounds__(256) void k_enc_cvt(const float* __restrict__ enc,
                                                 const int* __restrict__ perm,
                                                 f16* __restrict__ enc16) {
  const int p = blockIdx.x, b = blockIdx.y;
  const float* src = enc + ((size_t)perm[b] * NP + p) * NE;
  f16* dst = enc16 + ((size_t)b * NP + p) * NE;
  const int i0 = threadIdx.x * 8;
  cvt8(src + i0, dst + i0);
}

// ---------------------------------------------------------------------------
// K5: h0/c0 = tanh(mean @ W + b) via MFMA. grid (8, 2). y=0 -> h16, y=1 -> c.
// ---------------------------------------------------------------------------
__global__ __launch_bounds__(256) void k_init_mfma(const f16* __restrict__ mean16,
                                                   const f16* __restrict__ ihWt,
                                                   const f16* __restrict__ icWt,
                                                   const float* __restrict__ ihb,
                                                   const float* __restrict__ icb,
                                                   f16* __restrict__ h16,
                                                   float* __restrict__ cst) {
  __shared__ __align__(16) f16 lA[64 * LDT];
  __shared__ __align__(16) f16 lB[64 * LDT];
  const int n0 = blockIdx.x * 64;
  const int which = blockIdx.y;
  const f16* Wt = which ? icWt : ihWt;
  const float* bias = which ? icb : ihb;
  const int tid = threadIdx.x, lane = tid & 63, wv = tid >> 6;
  const int col = lane & 15, quad = lane >> 4;
  f32x4 acc[4] = {};
  for (int k0 = 0; k0 < NE; k0 += 32) {
    stage16(mean16, NE, k0, lA, tid);
    stage16(Wt + (size_t)n0 * NE, NE, k0, lB, tid);
    __syncthreads();
    mfma_step<4>(lA, lB, wv, col, quad, acc);
    __syncthreads();
  }
#pragma unroll
  for (int ns = 0; ns < 4; ++ns) {
    const int n = n0 + ns * 16 + col;
#pragma unroll
    for (int rr = 0; rr < 4; ++rr) {
      const int m = wv * 16 + quad * 4 + rr;
      const float v = tanhf(acc[ns][rr] + bias[n]);
      if (which == 0) h16[(size_t)m * ND + n] = (f16)v;
      else            cst[(size_t)m * ND + n] = v;
    }
  }
}

// ---------------------------------------------------------------------------
// K6: att1 = enc_sorted @ enc_att_W + b  -> f16. grid (8, 196).
// ---------------------------------------------------------------------------
template <bool E16>
__global__ __launch_bounds__(256) void k_att1_mfma(const float* __restrict__ encf,
                                                   const f16* __restrict__ enc16,
                                                   const int* __restrict__ perm,
                                                   const f16* __restrict__ eaWt,
                                                   const float* __restrict__ eab,
                                                   f16* __restrict__ att1) {
  __shared__ __align__(16) f16 lA[64 * LDT];
  __shared__ __align__(16) f16 lB[64 * LDT];
  __shared__ int rowoff[64];
  const int r0 = blockIdx.y * 64;
  const int n0 = blockIdx.x * 64;
  const int tid = threadIdx.x, lane = tid & 63, wv = tid >> 6;
  const int col = lane & 15, quad = lane >> 4;
  if (!E16) {
    if (tid < 64) {
      const int r = r0 + tid;
      const int b = r / NP, p = r - b * NP;
      rowoff[tid] = (perm[b] * NP + p) * NE;
    }
  }
  __syncthreads();
  f32x4 acc[4] = {};
  for (int k0 = 0; k0 < NE; k0 += 32) {
    if (E16) {
      stage16(enc16 + (size_t)r0 * NE, NE, k0, lA, tid);
    } else {
      const int row = tid >> 2, seg = tid & 3;
      cvt8(encf + (size_t)rowoff[row] + k0 + seg * 8, &lA[row * LDT + seg * 8]);
    }
    stage16(eaWt + (size_t)n0 * NE, NE, k0, lB, tid);
    __syncthreads();
    mfma_step<4>(lA, lB, wv, col, quad, acc);
    __syncthreads();
  }
#pragma unroll
  for (int ns = 0; ns < 4; ++ns) {
    const int n = n0 + ns * 16 + col;
#pragma unroll
    for (int rr = 0; rr < 4; ++rr) {
      const int r = r0 + wv * 16 + quad * 4 + rr;
      att1[(size_t)r * NA + n] = (f16)(acc[ns][rr] + eab[n]);
    }
  }
}

// ---------------------------------------------------------------------------
// K7 (per step): fused h-GEMM -> att2 / gate / hh. 72 blocks:
//   [0,8)   att2 = h@dec_att_W + b        (f16 ws weight)
//   [8,40)  gate = sigmoid(h@f_beta_W+b)  (f16 ws weight)
//   [40,72) hh   = h@W_hh^T + b_hh + b_ih (fp32 N-major, convert on stage)
// ---------------------------------------------------------------------------
__global__ __launch_bounds__(256) void k_hgemm_mfma(const f16* __restrict__ h16,
                                                    const f16* __restrict__ daWt,
                                                    const float* __restrict__ dab,
                                                    const f16* __restrict__ fbWt,
                                                    const float* __restrict__ fbb,
                                                    const float* __restrict__ Whh,
                                                    const float* __restrict__ bhh,
                                                    const float* __restrict__ bih,
                                                    float* __restrict__ att2,
                                                    float* __restrict__ gate,
                                                    float* __restrict__ hh) {
  __shared__ __align__(16) f16 lA[64 * LDT];
  __shared__ __align__(16) f16 lB[64 * LDT];
  const int bx = blockIdx.x;
  int mode, n0l;
  const f16* Bf16 = nullptr;
  if (bx < 8)       { mode = 0; n0l = bx * 64;        Bf16 = daWt; }
  else if (bx < 40) { mode = 1; n0l = (bx - 8) * 64;  Bf16 = fbWt; }
  else              { mode = 2; n0l = (bx - 40) * 64; }
  const int tid = threadIdx.x, lane = tid & 63, wv = tid >> 6;
  const int col = lane & 15, quad = lane >> 4;
  f32x4 acc[4] = {};
  for (int k0 = 0; k0 < ND; k0 += 32) {
    stage16(h16, ND, k0, lA, tid);
    if (mode == 2) {
      const int row = tid >> 2, seg = tid & 3;
      cvt8(Whh + (size_t)(n0l + row) * ND + k0 + seg * 8, &lB[row * LDT + seg * 8]);
    } else {
      stage16(Bf16 + (size_t)n0l * ND, ND, k0, lB, tid);
    }
    __syncthreads();
    mfma_step<4>(lA, lB, wv, col, quad, acc);
    __syncthreads();
  }
#pragma unroll
  for (int ns = 0; ns < 4; ++ns) {
    const int n = n0l + ns * 16 + col;
#pragma unroll
    for (int rr = 0; rr < 4; ++rr) {
      const int m = wv * 16 + quad * 4 + rr;
      const float v = acc[ns][rr];
      if (mode == 0)      att2[(size_t)m * NA + n] = v + dab[n];
      else if (mode == 1) gate[(size_t)m * NE + n] = sigmoidf_(v + fbb[n]);
      else                hh[(size_t)m * NE + n] = v + bhh[n] + bih[n];
    }
  }
}

// ---------------------------------------------------------------------------
// K8 (per step): attention logits + softmax. One block per b.
// Per-lane registers hold its 8 att2/full_att_W values (reused over all p).
// ---------------------------------------------------------------------------
__global__ __launch_bounds__(256) void k_attn(const f16* __restrict__ att1,
                                              const float* __restrict__ att2,
                                              const float* __restrict__ fullW,
                                              const int* __restrict__ declen, int t,
                                              float* __restrict__ alpha_ws,
                                              float* __restrict__ out_alphas) {
  const int b = blockIdx.x;
  const int tid = threadIdx.x, wv = tid >> 6, lane = tid & 63;
  float a2r[8], fwr[8];
  {
    const float4* A2 = (const float4*)(att2 + (size_t)b * NA + lane * 8);
    const float4* FW = (const float4*)(fullW + lane * 8);
    const float4 q0 = A2[0], q1 = A2[1], w0 = FW[0], w1 = FW[1];
    a2r[0] = q0.x; a2r[1] = q0.y; a2r[2] = q0.z; a2r[3] = q0.w;
    a2r[4] = q1.x; a2r[5] = q1.y; a2r[6] = q1.z; a2r[7] = q1.w;
    fwr[0] = w0.x; fwr[1] = w0.y; fwr[2] = w0.z; fwr[3] = w0.w;
    fwr[4] = w1.x; fwr[5] = w1.y; fwr[6] = w1.z; fwr[7] = w1.w;
  }
  __shared__ float e[200];
  __shared__ float sred[256];
  for (int p = wv; p < NP; p += 4) {
    const f16x8 row = *(const f16x8*)(att1 + ((size_t)b * NP + p) * NA + lane * 8);
    float acc = 0.0f;
#pragma unroll
    for (int j = 0; j < 8; ++j) acc += fmaxf((float)row[j] + a2r[j], 0.0f) * fwr[j];
#pragma unroll
    for (int off = 32; off > 0; off >>= 1) acc += __shfl_down(acc, off, 64);
    if (lane == 0) e[p] = acc;
  }
  __syncthreads();
  sred[tid] = (tid < NP) ? e[tid] : -INFINITY;
  __syncthreads();
  for (int s = 128; s > 0; s >>= 1) {
    if (tid < s) sred[tid] = fmaxf(sred[tid], sred[tid + s]);
    __syncthreads();
  }
  const float m = sred[0];
  __syncthreads();
  const float ex = (tid < NP) ? expf(e[tid] - m) : 0.0f;
  sred[tid] = ex;
  __syncthreads();
  for (int s = 128; s > 0; s >>= 1) {
    if (tid < s) sred[tid] += sred[tid + s];
    __syncthreads();
  }
  const float inv = 1.0f / sred[0];
  if (tid < NP) {
    const float al = ex * inv;
    alpha_ws[(size_t)b * NP + tid] = al;
    const bool act = t < declen[b];
    out_alphas[((size_t)b * NTD + t) * NP + tid] = act ? al : 0.0f;
  }
}

// ---------------------------------------------------------------------------
// K9 (per step): awe + gate + build x16. grid (5, 64):
//   x<4: 512-ch slice: x16[b][512+c] = f16(gate*sum_p alpha*enc)
//   x==4: x16[b][0..512) = f16(emb[cap])
// ---------------------------------------------------------------------------
template <bool E16>
__global__ __launch_bounds__(256) void k_awe_x(const float* __restrict__ encf,
                                               const f16* __restrict__ enc16,
                                               const int* __restrict__ perm,
                                               const float* __restrict__ alpha_ws,
                                               const float* __restrict__ gate,
                                               const float* __restrict__ emb,
                                               const int* __restrict__ caps_s, int t,
                                               f16* __restrict__ x16) {
  const int s = blockIdx.x, b = blockIdx.y, tid = threadIdx.x;
  if (s == 4) {
    const int cap = caps_s[b * NT_CAP + t];
    const int i0 = tid * 2;
    const float2 v = *(const float2*)(emb + (size_t)cap * 512 + i0);
    x16[(size_t)b * 2560 + i0] = (f16)v.x;
    x16[(size_t)b * 2560 + i0 + 1] = (f16)v.y;
    return;
  }
  __shared__ float al[NP];
  if (tid < NP) al[tid] = alpha_ws[(size_t)b * NP + tid];
  __syncthreads();
  const int c0 = s * 512 + tid * 2;
  float a0 = 0.0f, a1 = 0.0f;
  if (E16) {
    const f16* base = enc16 + (size_t)b * NP * NE + c0;
    for (int p = 0; p < NP; ++p) {
      const f16x2 v = *(const f16x2*)&base[(size_t)p * NE];
      a0 += al[p] * (float)v[0];
      a1 += al[p] * (float)v[1];
    }
  } else {
    const float* base = encf + (size_t)perm[b] * NP * NE + c0;
    for (int p = 0; p < NP; ++p) {
      const float2 v = *(const float2*)&base[(size_t)p * NE];
      a0 += al[p] * v.x;
      a1 += al[p] * v.y;
    }
  }
  const float g0 = gate[(size_t)b * NE + c0], g1 = gate[(size_t)b * NE + c0 + 1];
  x16[(size_t)b * 2560 + 512 + c0] = (f16)(a0 * g0);
  x16[(size_t)b * 2560 + 512 + c0 + 1] = (f16)(a1 * g1);
}

// ---------------------------------------------------------------------------
// K10 (per step): x@W_ih^T (+hh) fused with LSTM cell. 64 blocks; block owns
// 8 d-columns x all 4 gates (32 W_ih rows). Epilogue pairs i/f and g/o via
// __shfl_down(.,8,16), updates c/h16 (masked), writes hnew16 (always).
// ---------------------------------------------------------------------------
__global__ __launch_bounds__(256) void k_xlstm_mfma(const f16* __restrict__ x16,
                                                    const float* __restrict__ Wih,
                                                    const float* __restrict__ hh,
                                                    const int* __restrict__ declen, int t,
                                                    float* __restrict__ cst,
                                                    f16* __restrict__ h16,
                                                    f16* __restrict__ hnew16) {
  __shared__ __align__(16) f16 lA[64 * LDT];
  __shared__ __align__(16) f16 lB[32 * LDT];
  const int d0 = blockIdx.x * 8;
  const int tid = threadIdx.x, lane = tid & 63, wv = tid >> 6;
  const int col = lane & 15, quad = lane >> 4;
  f32x4 acc[2] = {};
  for (int k0 = 0; k0 < 2560; k0 += 32) {
    stage16(x16, 2560, k0, lA, tid);
    if (tid < 128) {
      const int row = tid >> 2, seg = tid & 3;  // row = jj in [0,32)
      const int n = (row >> 3) * 512 + d0 + (row & 7);
      cvt8(Wih + (size_t)n * 2560 + k0 + seg * 8, &lB[row * LDT + seg * 8]);
    }
    __syncthreads();
    mfma_step<2>(lA, lB, wv, col, quad, acc);
    __syncthreads();
  }
  // add hh (biases + h@W_hh^T already included)
#pragma unroll
  for (int t2 = 0; t2 < 2; ++t2) {
    const int jj = t2 * 16 + col;
    const int n = (jj >> 3) * 512 + d0 + (jj & 7);
#pragma unroll
    for (int rr = 0; rr < 4; ++rr) {
      const int m = wv * 16 + quad * 4 + rr;
      acc[t2][rr] += hh[(size_t)m * NE + n];
    }
  }
  float fsh[4], osh[4];
#pragma unroll
  for (int rr = 0; rr < 4; ++rr) {
    fsh[rr] = __shfl_down(acc[0][rr], 8, 16);
    osh[rr] = __shfl_down(acc[1][rr], 8, 16);
  }
  if (col < 8) {
    const int d = d0 + col;
#pragma unroll
    for (int rr = 0; rr < 4; ++rr) {
      const int m = wv * 16 + quad * 4 + rr;
      const float iv = sigmoidf_(acc[0][rr]);
      const float fv = sigmoidf_(fsh[rr]);
      const float gv = tanhf(acc[1][rr]);
      const float ov = sigmoidf_(osh[rr]);
      const float cold = cst[(size_t)m * ND + d];
      const float cn = fv * cold + iv * gv;
      const float hn = ov * tanhf(cn);
      hnew16[(size_t)m * ND + d] = (f16)hn;
      if (t < declen[m]) {
        cst[(size_t)m * ND + d] = cn;
        h16[(size_t)m * ND + d] = (f16)hn;
      }
    }
  }
}

// ---------------------------------------------------------------------------
// K11 (per step): preds = hnew16 @ fc_W + fc_b (masked). 157 blocks.
// fc_W is fp32 K-major; transpose-converted during LDS staging.
// ---------------------------------------------------------------------------
__global__ __launch_bounds__(256) void k_fc_mfma(const f16* __restrict__ hnew16,
                                                 const float* __restrict__ fcW,
                                                 const float* __restrict__ fcb,
                                                 const int* __restrict__ declen, int t,
                                                 float* __restrict__ out_pred) {
  __shared__ __align__(16) f16 lA[64 * LDT];
  __shared__ __align__(16) f16 lB[64 * LDT];
  const int n0 = blockIdx.x * 64;
  const int tid = threadIdx.x, lane = tid & 63, wv = tid >> 6;
  const int col = lane & 15, quad = lane >> 4;
  f32x4 acc[4] = {};
  for (int k0 = 0; k0 < ND; k0 += 32) {
    stage16(hnew16, ND, k0, lA, tid);
    {
      const int kk = tid >> 3, ng = tid & 7;
      const int nb = n0 + ng * 8;
      float vals[8];
      if (nb < NV) {
        const float* p = fcW + (size_t)(k0 + kk) * NV + nb;
        const float4 a = *(const float4*)p;
        const float4 b2 = *(const float4*)(p + 4);
        vals[0] = a.x; vals[1] = a.y; vals[2] = a.z; vals[3] = a.w;
        vals[4] = b2.x; vals[5] = b2.y; vals[6] = b2.z; vals[7] = b2.w;
      } else {
#pragma unroll
        for (int j = 0; j < 8; ++j) vals[j] = 0.0f;
      }
#pragma unroll
      for (int j = 0; j < 8; ++j) lB[(ng * 8 + j) * LDT + kk] = (f16)vals[j];
    }
    __syncthreads();
    mfma_step<4>(lA, lB, wv, col, quad, acc);
    __syncthreads();
  }
#pragma unroll
  for (int ns = 0; ns < 4; ++ns) {
    const int n = n0 + ns * 16 + col;
    if (n < NV) {
#pragma unroll
      for (int rr = 0; rr < 4; ++rr) {
        const int m = wv * 16 + quad * 4 + rr;
        const bool act = t < declen[m];
        out_pred[((size_t)m * NTD + t) * NV + n] = act ? (acc[ns][rr] + fcb[n]) : 0.0f;
      }
    }
  }
}

}  // namespace

extern "C" void kernel_launch(void* const* d_in, const int* in_sizes, int n_in,
                              void* d_out, int out_size, void* d_ws, size_t ws_size,
                              hipStream_t stream) {
  const float* enc        = (const float*)d_in[0];
  const int*   caps       = (const int*)d_in[1];
  const int*   caplen     = (const int*)d_in[2];
  const float* emb        = (const float*)d_in[3];
  const float* enc_att_W  = (const float*)d_in[4];
  const float* enc_att_b  = (const float*)d_in[5];
  const float* dec_att_W  = (const float*)d_in[6];
  const float* dec_att_b  = (const float*)d_in[7];
  const float* full_att_W = (const float*)d_in[8];
  // d_in[9] full_att_b: shift-invariant under softmax, unused.
  const float* init_h_W   = (const float*)d_in[10];
  const float* init_h_b   = (const float*)d_in[11];
  const float* init_c_W   = (const float*)d_in[12];
  const float* init_c_b   = (const float*)d_in[13];
  const float* f_beta_W   = (const float*)d_in[14];
  const float* f_beta_b   = (const float*)d_in[15];
  const float* W_ih       = (const float*)d_in[16];
  const float* b_ih       = (const float*)d_in[17];
  const float* W_hh       = (const float*)d_in[18];
  const float* b_hh       = (const float*)d_in[19];
  const float* fc_W       = (const float*)d_in[20];
  const float* fc_b       = (const float*)d_in[21];

  char* ws = (char*)d_ws;
  f16*   att1   = (f16*)(ws + OFF_ATT1);
  f16*   eaWt   = (f16*)(ws + OFF_EAW);
  f16*   daWt   = (f16*)(ws + OFF_DAW);
  f16*   fbWt   = (f16*)(ws + OFF_FBW);
  f16*   ihWt   = (f16*)(ws + OFF_IHW);
  f16*   icWt   = (f16*)(ws + OFF_ICW);
  float* mean   = (float*)(ws + OFF_MEAN);
  f16*   mean16 = (f16*)(ws + OFF_MEAN16);
  f16*   h16    = (f16*)(ws + OFF_H16);
  f16*   hnew16 = (f16*)(ws + OFF_HNEW16);
  float* cst    = (float*)(ws + OFF_C);
  float* att2   = (float*)(ws + OFF_ATT2);
  float* gate   = (float*)(ws + OFF_GATE);
  float* hh     = (float*)(ws + OFF_HH);
  float* alpha  = (float*)(ws + OFF_ALPHA);
  f16*   x16    = (f16*)(ws + OFF_X16);
  int*   wsi    = (int*)(ws + OFF_INT);
  int*   perm   = wsi;
  int*   declen = wsi + 64;
  int*   caps_s = wsi + 128;
  f16*   enc16  = (f16*)(ws + OFF_ENC16);

  const bool full = ws_size >= FULL_BYTES;

  float* out         = (float*)d_out;
  float* out_pred    = out;
  float* out_caps    = out_pred + (size_t)NB * NTD * NV;
  float* out_declen  = out_caps + (size_t)NB * NT_CAP;
  float* out_alphas  = out_declen + NB;
  float* out_sortind = out_alphas + (size_t)NB * NTD * NP;

  k_sort<<<1, 64, 0, stream>>>(caplen, caps, perm, declen, caps_s,
                               out_caps, out_declen, out_sortind);
  k_tconv<<<dim3(16, 64), 256, 0, stream>>>(enc_att_W, eaWt, 2048, 512);
  k_tconv<<<dim3(16, 16), 256, 0, stream>>>(dec_att_W, daWt, 512, 512);
  k_tconv<<<dim3(64, 16), 256, 0, stream>>>(f_beta_W, fbWt, 512, 2048);
  k_tconv<<<dim3(16, 64), 256, 0, stream>>>(init_h_W, ihWt, 2048, 512);
  k_tconv<<<dim3(16, 64), 256, 0, stream>>>(init_c_W, icWt, 2048, 512);
  k_mean<<<dim3(4, 64), 256, 0, stream>>>(enc, perm, mean, mean16);
  if (full) k_enc_cvt<<<dim3(196, 64), 256, 0, stream>>>(enc, perm, enc16);
  k_init_mfma<<<dim3(8, 2), 256, 0, stream>>>(mean16, ihWt, icWt, init_h_b, init_c_b,
                                              h16, cst);
  if (full)
    k_att1_mfma<true><<<dim3(8, 196), 256, 0, stream>>>(enc, enc16, perm, eaWt,
                                                        enc_att_b, att1);
  else
    k_att1_mfma<false><<<dim3(8, 196), 256, 0, stream>>>(enc, enc16, perm, eaWt,
                                                         enc_att_b, att1);

  for (int t = 0; t < NTD; ++t) {
    k_hgemm_mfma<<<72, 256, 0, stream>>>(h16, daWt, dec_att_b, fbWt, f_beta_b,
                                         W_hh, b_hh, b_ih, att2, gate, hh);
    k_attn<<<NB, 256, 0, stream>>>(att1, att2, full_att_W, declen, t, alpha, out_alphas);
    if (full)
      k_awe_x<true><<<dim3(5, 64), 256, 0, stream>>>(enc, enc16, perm, alpha, gate,
                                                     emb, caps_s, t, x16);
    else
      k_awe_x<false><<<dim3(5, 64), 256, 0, stream>>>(enc, enc16, perm, alpha, gate,
                                                      emb, caps_s, t, x16);
    k_xlstm_mfma<<<64, 256, 0, stream>>>(x16, W_ih, hh, declen, t, cst, h16, hnew16);
    k_fc_mfma<<<157, 256, 0, stream>>>(hnew16, fc_W, fc_b, declen, t, out_pred);
  }
}

// Round 3
// 2812.505 us; speedup vs baseline: 1.9149x; 1.0557x over previous
//
#include <hip/hip_runtime.h>
#include <cstddef>

// ---------------------------------------------------------------------------
// DecoderWithAttention forward — Round 3.
// All per-step weights f16 in ws (fc_W transposed, W_ih|W_hh concatenated).
// LSTM GEMM consumes xcat=[emb|awe|h] (K=3072), cell fused in epilogue.
// att1 retiled to 64x256 blocks (2x A-reads instead of 8x).
// ---------------------------------------------------------------------------

namespace {

typedef _Float16 f16;
typedef f16 f16x8 __attribute__((ext_vector_type(8)));
typedef f16 f16x4 __attribute__((ext_vector_type(4)));
typedef f16 f16x2 __attribute__((ext_vector_type(2)));
typedef float f32x4 __attribute__((ext_vector_type(4)));

constexpr int NB = 64, NP = 196, NE = 2048, NA = 512, ND = 512, NV = 10000;
constexpr int NT_CAP = 21, NTD = 20;
constexpr int KC = 3072;   // xcat K: 512 emb + 2048 awe + 512 h
constexpr int LDT = 40;    // LDS row stride (f16): 80 B, 2-way-conflict max

// ---- workspace byte offsets ----
constexpr size_t OFF_ATT1   = 0;           // f16 [12544][512]
constexpr size_t OFF_DAW    = 12845056;    // f16 [512][512]
constexpr size_t OFF_FBW    = 13369344;    // f16 [2048][512]
constexpr size_t OFF_EAW    = 15466496;    // f16 [512][2048]   (preamble only)
constexpr size_t OFF_IHW    = 17563648;    // f16 [512][2048]   (preamble only)
constexpr size_t OFF_ICW    = 19660800;    // f16 [512][2048]   (preamble only)
constexpr size_t OFF_FCW    = 15466496;    // f16 [10048][512]  ALIASES eaW/ihW/icW
constexpr size_t OFF_WCAT   = 25755648;    // f16 [2048][3072]
constexpr size_t OFF_MEAN16 = 38338560;    // f16 [64][2048]
constexpr size_t OFF_H16    = 38600704;    // f16 [64][512]
constexpr size_t OFF_HNEW16 = 38666240;    // f16 [64][512]
constexpr size_t OFF_C      = 38731776;    // f32 [64][512]
constexpr size_t OFF_ATT2   = 38862848;    // f32 [64][512]
constexpr size_t OFF_GATE   = 38993920;    // f32 [64][2048]
constexpr size_t OFF_ALPHA  = 39518208;    // f32 [64][200]
constexpr size_t OFF_XCAT   = 39569408;    // f16 [64][3072]
constexpr size_t OFF_INT    = 39962624;    // perm/declen/caps
constexpr size_t OFF_ENC16  = 39970816;    // f16 [64][196][2048] (optional)
constexpr size_t FULL_BYTES = 91351040;

__device__ __forceinline__ float sigmoidf_(float x) { return 1.0f / (1.0f + expf(-x)); }

// stage 64 rows x 32 k of f16 into LDS (256 threads, 16 B each)
__device__ __forceinline__ void stage16(const f16* __restrict__ src, int lda, int k0,
                                        f16* __restrict__ lds, int tid) {
  const int row = tid >> 2, seg = tid & 3;
  *(f16x8*)&lds[row * LDT + seg * 8] =
      *(const f16x8*)&src[(size_t)row * lda + k0 + seg * 8];
}

// convert 8 consecutive fp32 -> 8 f16 at dst
__device__ __forceinline__ void cvt8(const float* __restrict__ p, f16* __restrict__ dst) {
  const float4 a = *(const float4*)p;
  const float4 b = *(const float4*)(p + 4);
  f16x8 v;
  v[0] = (f16)a.x; v[1] = (f16)a.y; v[2] = (f16)a.z; v[3] = (f16)a.w;
  v[4] = (f16)b.x; v[5] = (f16)b.y; v[6] = (f16)b.z; v[7] = (f16)b.w;
  *(f16x8*)dst = v;
}

template <int NT>
__device__ __forceinline__ void mfma_step(const f16* __restrict__ lA, const f16* __restrict__ lB,
                                          int wv, int col, int quad, f32x4* acc) {
  const f16x8 a = *(const f16x8*)&lA[(wv * 16 + col) * LDT + quad * 8];
#pragma unroll
  for (int ns = 0; ns < NT; ++ns) {
    const f16x8 b = *(const f16x8*)&lB[(ns * 16 + col) * LDT + quad * 8];
    acc[ns] = __builtin_amdgcn_mfma_f32_16x16x32_f16(a, b, acc[ns], 0, 0, 0);
  }
}

// ---------------------------------------------------------------------------
// K1: stable descending argsort + gathered caps/declen/sortind outputs.
// ---------------------------------------------------------------------------
__global__ void k_sort(const int* __restrict__ cap_len, const int* __restrict__ caps,
                       int* __restrict__ perm, int* __restrict__ declen,
                       int* __restrict__ caps_sorted,
                       float* __restrict__ out_caps, float* __restrict__ out_declen,
                       float* __restrict__ out_sortind) {
  __shared__ int cl[NB];
  __shared__ int pr[NB];
  const int i = threadIdx.x;
  int c = cap_len[i];
  if (c < 1) c = 1;
  cl[i] = c;
  __syncthreads();
  int rank = 0;
  for (int j = 0; j < NB; ++j) {
    const int cj = cl[j];
    if (cj > c || (cj == c && j < i)) rank++;
  }
  pr[rank] = i;
  __syncthreads();
  const int src = pr[i];
  perm[i] = src;
  const int dl = cl[src] - 1;
  declen[i] = dl;
  out_declen[i] = (float)dl;
  out_sortind[i] = (float)src;
  for (int j = 0; j < NT_CAP; ++j) {
    const int v = caps[src * NT_CAP + j];
    caps_sorted[i * NT_CAP + j] = v;
    out_caps[i * NT_CAP + j] = (float)v;
  }
}

// ---------------------------------------------------------------------------
// K2: transpose-convert fp32 [K][Nsrc] (K-major) -> f16 [N][K]; zero if n>=Nsrc.
// ---------------------------------------------------------------------------
__global__ __launch_bounds__(256) void k_tconv(const float* __restrict__ src,
                                               f16* __restrict__ dst, int K, int Nsrc) {
  __shared__ float tile[32][33];
  const int n0 = blockIdx.x * 32, k0 = blockIdx.y * 32;
  const int tid = threadIdx.x;
  const int a = tid & 31, q = tid >> 5;
#pragma unroll
  for (int r = 0; r < 4; ++r) {
    const int kl = q * 4 + r;
    tile[a][kl] = (n0 + a < Nsrc) ? src[(size_t)(k0 + kl) * Nsrc + n0 + a] : 0.0f;
  }
  __syncthreads();
#pragma unroll
  for (int r = 0; r < 4; ++r) {
    const int nl = q * 4 + r;
    dst[(size_t)(n0 + nl) * K + k0 + a] = (f16)tile[nl][a];
  }
}

// ---------------------------------------------------------------------------
// K2b: Wcat[n][k] = f16( k<2560 ? W_ih[n][k] : W_hh[n][k-2560] ). grid 2048.
// ---------------------------------------------------------------------------
__global__ __launch_bounds__(256) void k_cvt_wcat(const float* __restrict__ Wih,
                                                  const float* __restrict__ Whh,
                                                  f16* __restrict__ Wcat) {
  const int n = blockIdx.x;
  for (int k = threadIdx.x; k < KC; k += 256) {
    const float v = (k < 2560) ? Wih[(size_t)n * 2560 + k] : Whh[(size_t)n * 512 + (k - 2560)];
    Wcat[(size_t)n * KC + k] = (f16)v;
  }
}

// ---------------------------------------------------------------------------
// K3: mean over P of sorted encoder rows -> mean16. grid (4, 64).
// ---------------------------------------------------------------------------
__global__ __launch_bounds__(256) void k_mean(const float* __restrict__ enc,
                                              const int* __restrict__ perm,
                                              f16* __restrict__ mean16) {
  const int b = blockIdx.y;
  const int c0 = blockIdx.x * 512 + threadIdx.x * 2;
  const float* base = enc + (size_t)perm[b] * NP * NE + c0;
  float a0 = 0.0f, a1 = 0.0f;
  for (int p = 0; p < NP; ++p) {
    const float2 v = *(const float2*)&base[(size_t)p * NE];
    a0 += v.x; a1 += v.y;
  }
  mean16[(size_t)b * NE + c0] = (f16)(a0 * (1.0f / (float)NP));
  mean16[(size_t)b * NE + c0 + 1] = (f16)(a1 * (1.0f / (float)NP));
}

// ---------------------------------------------------------------------------
// K4 (FULL only): enc16[b][p][c] = f16(enc[perm[b]][p][c]). grid (196, 64).
// ---------------------------------------------------------------------------
__global__ __launch_bounds__(256) void k_enc_cvt(const float* __restrict__ enc,
                                                 const int* __restrict__ perm,
                                                 f16* __restrict__ enc16) {
  const int p = blockIdx.x, b = blockIdx.y;
  const float* src = enc + ((size_t)perm[b] * NP + p) * NE;
  f16* dst = enc16 + ((size_t)b * NP + p) * NE;
  const int i0 = threadIdx.x * 8;
  cvt8(src + i0, dst + i0);
}

// ---------------------------------------------------------------------------
// K5: h0/c0 = tanh(mean @ W + b) via MFMA. grid (8, 2).
// ---------------------------------------------------------------------------
__global__ __launch_bounds__(256) void k_init_mfma(const f16* __restrict__ mean16,
                                                   const f16* __restrict__ ihWt,
                                                   const f16* __restrict__ icWt,
                                                   const float* __restrict__ ihb,
                                                   const float* __restrict__ icb,
                                                   f16* __restrict__ h16,
                                                   float* __restrict__ cst) {
  __shared__ __align__(16) f16 lA[64 * LDT];
  __shared__ __align__(16) f16 lB[64 * LDT];
  const int n0 = blockIdx.x * 64;
  const int which = blockIdx.y;
  const f16* Wt = which ? icWt : ihWt;
  const float* bias = which ? icb : ihb;
  const int tid = threadIdx.x, lane = tid & 63, wv = tid >> 6;
  const int col = lane & 15, quad = lane >> 4;
  f32x4 acc[4] = {};
  for (int k0 = 0; k0 < NE; k0 += 32) {
    stage16(mean16, NE, k0, lA, tid);
    stage16(Wt + (size_t)n0 * NE, NE, k0, lB, tid);
    __syncthreads();
    mfma_step<4>(lA, lB, wv, col, quad, acc);
    __syncthreads();
  }
#pragma unroll
  for (int ns = 0; ns < 4; ++ns) {
    const int n = n0 + ns * 16 + col;
#pragma unroll
    for (int rr = 0; rr < 4; ++rr) {
      const int m = wv * 16 + quad * 4 + rr;
      const float v = tanhf(acc[ns][rr] + bias[n]);
      if (which == 0) h16[(size_t)m * ND + n] = (f16)v;
      else            cst[(size_t)m * ND + n] = v;
    }
  }
}

// ---------------------------------------------------------------------------
// K6: att1 = enc @ enc_att_W + b -> f16. grid (2, 196): 64 rows x 256 cols.
// enc16 read twice total (vs 8x in R2).
// ---------------------------------------------------------------------------
template <bool E16>
__global__ __launch_bounds__(256) void k_att1_mfma(const float* __restrict__ encf,
                                                   const f16* __restrict__ enc16,
                                                   const int* __restrict__ perm,
                                                   const f16* __restrict__ eaWt,
                                                   const float* __restrict__ eab,
                                                   f16* __restrict__ att1) {
  __shared__ __align__(16) f16 lA[64 * LDT];
  __shared__ __align__(16) f16 lB[256 * LDT];
  __shared__ int rowoff[64];
  const int r0 = blockIdx.y * 64;
  const int n0 = blockIdx.x * 256;
  const int tid = threadIdx.x, lane = tid & 63, wv = tid >> 6;
  const int col = lane & 15, quad = lane >> 4;
  if (!E16) {
    if (tid < 64) {
      const int r = r0 + tid;
      const int b = r / NP, p = r - b * NP;
      rowoff[tid] = (perm[b] * NP + p) * NE;
    }
    __syncthreads();
  }
  f32x4 acc[16] = {};
  for (int k0 = 0; k0 < NE; k0 += 32) {
    if (E16) {
      stage16(enc16 + (size_t)r0 * NE, NE, k0, lA, tid);
    } else {
      const int row = tid >> 2, seg = tid & 3;
      cvt8(encf + (size_t)rowoff[row] + k0 + seg * 8, &lA[row * LDT + seg * 8]);
    }
    {
      const int row0 = tid >> 2, seg = tid & 3;
#pragma unroll
      for (int u = 0; u < 4; ++u) {
        const int row = row0 + 64 * u;
        *(f16x8*)&lB[row * LDT + seg * 8] =
            *(const f16x8*)&eaWt[(size_t)(n0 + row) * NE + k0 + seg * 8];
      }
    }
    __syncthreads();
    mfma_step<16>(lA, lB, wv, col, quad, acc);
    __syncthreads();
  }
#pragma unroll
  for (int ns = 0; ns < 16; ++ns) {
    const int n = n0 + ns * 16 + col;
#pragma unroll
    for (int rr = 0; rr < 4; ++rr) {
      const int r = r0 + wv * 16 + quad * 4 + rr;
      att1[(size_t)r * NA + n] = (f16)(acc[ns][rr] + eab[n]);
    }
  }
}

// ---------------------------------------------------------------------------
// K7 (per step): h-GEMM -> att2 (8 blocks) / gate (32 blocks). f16 weights.
// ---------------------------------------------------------------------------
__global__ __launch_bounds__(256) void k_hgemm_mfma(const f16* __restrict__ h16,
                                                    const f16* __restrict__ daWt,
                                                    const float* __restrict__ dab,
                                                    const f16* __restrict__ fbWt,
                                                    const float* __restrict__ fbb,
                                                    float* __restrict__ att2,
                                                    float* __restrict__ gate) {
  __shared__ __align__(16) f16 lA[64 * LDT];
  __shared__ __align__(16) f16 lB[64 * LDT];
  const int bx = blockIdx.x;
  const int mode = (bx < 8) ? 0 : 1;
  const int n0l = (mode == 0) ? bx * 64 : (bx - 8) * 64;
  const f16* Bf16 = (mode == 0) ? daWt : fbWt;
  const int tid = threadIdx.x, lane = tid & 63, wv = tid >> 6;
  const int col = lane & 15, quad = lane >> 4;
  f32x4 acc[4] = {};
  for (int k0 = 0; k0 < ND; k0 += 32) {
    stage16(h16, ND, k0, lA, tid);
    stage16(Bf16 + (size_t)n0l * ND, ND, k0, lB, tid);
    __syncthreads();
    mfma_step<4>(lA, lB, wv, col, quad, acc);
    __syncthreads();
  }
#pragma unroll
  for (int ns = 0; ns < 4; ++ns) {
    const int n = n0l + ns * 16 + col;
#pragma unroll
    for (int rr = 0; rr < 4; ++rr) {
      const int m = wv * 16 + quad * 4 + rr;
      const float v = acc[ns][rr];
      if (mode == 0) att2[(size_t)m * NA + n] = v + dab[n];
      else           gate[(size_t)m * NE + n] = sigmoidf_(v + fbb[n]);
    }
  }
}

// ---------------------------------------------------------------------------
// K8 (per step): attention logits + softmax. One block per b.
// ---------------------------------------------------------------------------
__global__ __launch_bounds__(256) void k_attn(const f16* __restrict__ att1,
                                              const float* __restrict__ att2,
                                              const float* __restrict__ fullW,
                                              const int* __restrict__ declen, int t,
                                              float* __restrict__ alpha_ws,
                                              float* __restrict__ out_alphas) {
  const int b = blockIdx.x;
  const int tid = threadIdx.x, wv = tid >> 6, lane = tid & 63;
  float a2r[8], fwr[8];
  {
    const float4* A2 = (const float4*)(att2 + (size_t)b * NA + lane * 8);
    const float4* FW = (const float4*)(fullW + lane * 8);
    const float4 q0 = A2[0], q1 = A2[1], w0 = FW[0], w1 = FW[1];
    a2r[0] = q0.x; a2r[1] = q0.y; a2r[2] = q0.z; a2r[3] = q0.w;
    a2r[4] = q1.x; a2r[5] = q1.y; a2r[6] = q1.z; a2r[7] = q1.w;
    fwr[0] = w0.x; fwr[1] = w0.y; fwr[2] = w0.z; fwr[3] = w0.w;
    fwr[4] = w1.x; fwr[5] = w1.y; fwr[6] = w1.z; fwr[7] = w1.w;
  }
  __shared__ float e[200];
  __shared__ float sred[256];
  for (int p = wv; p < NP; p += 4) {
    const f16x8 row = *(const f16x8*)(att1 + ((size_t)b * NP + p) * NA + lane * 8);
    float acc = 0.0f;
#pragma unroll
    for (int j = 0; j < 8; ++j) acc += fmaxf((float)row[j] + a2r[j], 0.0f) * fwr[j];
#pragma unroll
    for (int off = 32; off > 0; off >>= 1) acc += __shfl_down(acc, off, 64);
    if (lane == 0) e[p] = acc;
  }
  __syncthreads();
  sred[tid] = (tid < NP) ? e[tid] : -INFINITY;
  __syncthreads();
  for (int s = 128; s > 0; s >>= 1) {
    if (tid < s) sred[tid] = fmaxf(sred[tid], sred[tid + s]);
    __syncthreads();
  }
  const float m = sred[0];
  __syncthreads();
  const float ex = (tid < NP) ? expf(e[tid] - m) : 0.0f;
  sred[tid] = ex;
  __syncthreads();
  for (int s = 128; s > 0; s >>= 1) {
    if (tid < s) sred[tid] += sred[tid + s];
    __syncthreads();
  }
  const float inv = 1.0f / sred[0];
  if (tid < NP) {
    const float al = ex * inv;
    alpha_ws[(size_t)b * NP + tid] = al;
    const bool act = t < declen[b];
    out_alphas[((size_t)b * NTD + t) * NP + tid] = act ? al : 0.0f;
  }
}

// ---------------------------------------------------------------------------
// K9 (per step): awe + gate + build xcat. grid (3, 64):
//   s<2:  1024-ch slice: xcat[b][512+c] = f16(gate*sum_p alpha*enc)
//   s==2: xcat[b][0:512)=emb[cap], xcat[b][2560:3072)=h16
// ---------------------------------------------------------------------------
template <bool E16>
__global__ __launch_bounds__(256) void k_awe_x(const float* __restrict__ encf,
                                               const f16* __restrict__ enc16,
                                               const int* __restrict__ perm,
                                               const float* __restrict__ alpha_ws,
                                               const float* __restrict__ gate,
                                               const float* __restrict__ emb,
                                               const int* __restrict__ caps_s,
                                               const f16* __restrict__ h16, int t,
                                               f16* __restrict__ xcat) {
  const int s = blockIdx.x, b = blockIdx.y, tid = threadIdx.x;
  if (s == 2) {
    const int cap = caps_s[b * NT_CAP + t];
    const int i0 = tid * 2;
    const float2 v = *(const float2*)(emb + (size_t)cap * 512 + i0);
    f16x2 ev; ev[0] = (f16)v.x; ev[1] = (f16)v.y;
    *(f16x2*)&xcat[(size_t)b * KC + i0] = ev;
    *(f16x2*)&xcat[(size_t)b * KC + 2560 + i0] = *(const f16x2*)&h16[(size_t)b * ND + i0];
    return;
  }
  __shared__ float al[NP];
  if (tid < NP) al[tid] = alpha_ws[(size_t)b * NP + tid];
  __syncthreads();
  const int c = s * 1024 + tid * 4;
  float a0 = 0.0f, a1 = 0.0f, a2 = 0.0f, a3 = 0.0f;
  if (E16) {
    const f16* base = enc16 + (size_t)b * NP * NE + c;
    for (int p = 0; p < NP; ++p) {
      const f16x4 v = *(const f16x4*)&base[(size_t)p * NE];
      const float ap = al[p];
      a0 += ap * (float)v[0]; a1 += ap * (float)v[1];
      a2 += ap * (float)v[2]; a3 += ap * (float)v[3];
    }
  } else {
    const float* base = encf + (size_t)perm[b] * NP * NE + c;
    for (int p = 0; p < NP; ++p) {
      const float4 v = *(const float4*)&base[(size_t)p * NE];
      const float ap = al[p];
      a0 += ap * v.x; a1 += ap * v.y; a2 += ap * v.z; a3 += ap * v.w;
    }
  }
  const float4 g = *(const float4*)&gate[(size_t)b * NE + c];
  f16x4 o;
  o[0] = (f16)(a0 * g.x); o[1] = (f16)(a1 * g.y);
  o[2] = (f16)(a2 * g.z); o[3] = (f16)(a3 * g.w);
  *(f16x4*)&xcat[(size_t)b * KC + 512 + c] = o;
}

// ---------------------------------------------------------------------------
// K10 (per step): gates = xcat @ Wcat^T + biases, fused LSTM cell.
// 128 blocks; block owns 4 d-cols x 4 gates (16 Wcat rows). mfma_step<1>.
// ---------------------------------------------------------------------------
__global__ __launch_bounds__(256) void k_xlstm_mfma(const f16* __restrict__ xcat,
                                                    const f16* __restrict__ Wcat,
                                                    const float* __restrict__ bih,
                                                    const float* __restrict__ bhh,
                                                    const int* __restrict__ declen, int t,
                                                    float* __restrict__ cst,
                                                    f16* __restrict__ h16,
                                                    f16* __restrict__ hnew16) {
  __shared__ __align__(16) f16 lA[64 * LDT];
  __shared__ __align__(16) f16 lB[16 * LDT];
  const int d0 = blockIdx.x * 4;
  const int tid = threadIdx.x, lane = tid & 63, wv = tid >> 6;
  const int col = lane & 15, quad = lane >> 4;
  f32x4 acc[1] = {};
  for (int k0 = 0; k0 < KC; k0 += 32) {
    stage16(xcat, KC, k0, lA, tid);
    if (tid < 64) {
      const int row = tid >> 2, seg = tid & 3;  // row in [0,16)
      const int n = (row >> 2) * 512 + d0 + (row & 3);
      *(f16x8*)&lB[row * LDT + seg * 8] =
          *(const f16x8*)&Wcat[(size_t)n * KC + k0 + seg * 8];
    }
    __syncthreads();
    mfma_step<1>(lA, lB, wv, col, quad, acc);
    __syncthreads();
  }
  const int n = (col >> 2) * 512 + d0 + (col & 3);
  const float bs = bih[n] + bhh[n];
  float v[4];
#pragma unroll
  for (int rr = 0; rr < 4; ++rr) v[rr] = acc[0][rr] + bs;
  float fsh[4], gsh[4], osh[4];
#pragma unroll
  for (int rr = 0; rr < 4; ++rr) {
    fsh[rr] = __shfl_down(v[rr], 4, 16);
    gsh[rr] = __shfl_down(v[rr], 8, 16);
    osh[rr] = __shfl_down(v[rr], 12, 16);
  }
  if (col < 4) {
    const int d = d0 + col;
#pragma unroll
    for (int rr = 0; rr < 4; ++rr) {
      const int m = wv * 16 + quad * 4 + rr;
      const float iv = sigmoidf_(v[rr]);
      const float fv = sigmoidf_(fsh[rr]);
      const float gv = tanhf(gsh[rr]);
      const float ov = sigmoidf_(osh[rr]);
      const float cold = cst[(size_t)m * ND + d];
      const float cn = fv * cold + iv * gv;
      const float hn = ov * tanhf(cn);
      hnew16[(size_t)m * ND + d] = (f16)hn;
      if (t < declen[m]) {
        cst[(size_t)m * ND + d] = cn;
        h16[(size_t)m * ND + d] = (f16)hn;
      }
    }
  }
}

// ---------------------------------------------------------------------------
// K11 (per step): preds = hnew16 @ fcWt^T + fc_b (masked). 157 blocks.
// ---------------------------------------------------------------------------
__global__ __launch_bounds__(256) void k_fc_mfma(const f16* __restrict__ hnew16,
                                                 const f16* __restrict__ fcWt,
                                                 const float* __restrict__ fcb,
                                                 const int* __restrict__ declen, int t,
                                                 float* __restrict__ out_pred) {
  __shared__ __align__(16) f16 lA[64 * LDT];
  __shared__ __align__(16) f16 lB[64 * LDT];
  const int n0 = blockIdx.x * 64;
  const int tid = threadIdx.x, lane = tid & 63, wv = tid >> 6;
  const int col = lane & 15, quad = lane >> 4;
  f32x4 acc[4] = {};
  for (int k0 = 0; k0 < ND; k0 += 32) {
    stage16(hnew16, ND, k0, lA, tid);
    stage16(fcWt + (size_t)n0 * ND, ND, k0, lB, tid);
    __syncthreads();
    mfma_step<4>(lA, lB, wv, col, quad, acc);
    __syncthreads();
  }
#pragma unroll
  for (int ns = 0; ns < 4; ++ns) {
    const int n = n0 + ns * 16 + col;
    if (n < NV) {
#pragma unroll
      for (int rr = 0; rr < 4; ++rr) {
        const int m = wv * 16 + quad * 4 + rr;
        const bool act = t < declen[m];
        out_pred[((size_t)m * NTD + t) * NV + n] = act ? (acc[ns][rr] + fcb[n]) : 0.0f;
      }
    }
  }
}

}  // namespace

extern "C" void kernel_launch(void* const* d_in, const int* in_sizes, int n_in,
                              void* d_out, int out_size, void* d_ws, size_t ws_size,
                              hipStream_t stream) {
  const float* enc        = (const float*)d_in[0];
  const int*   caps       = (const int*)d_in[1];
  const int*   caplen     = (const int*)d_in[2];
  const float* emb        = (const float*)d_in[3];
  const float* enc_att_W  = (const float*)d_in[4];
  const float* enc_att_b  = (const float*)d_in[5];
  const float* dec_att_W  = (const float*)d_in[6];
  const float* dec_att_b  = (const float*)d_in[7];
  const float* full_att_W = (const float*)d_in[8];
  // d_in[9] full_att_b: shift-invariant under softmax, unused.
  const float* init_h_W   = (const float*)d_in[10];
  const float* init_h_b   = (const float*)d_in[11];
  const float* init_c_W   = (const float*)d_in[12];
  const float* init_c_b   = (const float*)d_in[13];
  const float* f_beta_W   = (const float*)d_in[14];
  const float* f_beta_b   = (const float*)d_in[15];
  const float* W_ih       = (const float*)d_in[16];
  const float* b_ih       = (const float*)d_in[17];
  const float* W_hh       = (const float*)d_in[18];
  const float* b_hh       = (const float*)d_in[19];
  const float* fc_W       = (const float*)d_in[20];
  const float* fc_b       = (const float*)d_in[21];

  char* ws = (char*)d_ws;
  f16*   att1   = (f16*)(ws + OFF_ATT1);
  f16*   daWt   = (f16*)(ws + OFF_DAW);
  f16*   fbWt   = (f16*)(ws + OFF_FBW);
  f16*   eaWt   = (f16*)(ws + OFF_EAW);
  f16*   ihWt   = (f16*)(ws + OFF_IHW);
  f16*   icWt   = (f16*)(ws + OFF_ICW);
  f16*   fcWt   = (f16*)(ws + OFF_FCW);   // aliases eaWt/ihWt/icWt (written after)
  f16*   Wcat   = (f16*)(ws + OFF_WCAT);
  f16*   mean16 = (f16*)(ws + OFF_MEAN16);
  f16*   h16    = (f16*)(ws + OFF_H16);
  f16*   hnew16 = (f16*)(ws + OFF_HNEW16);
  float* cst    = (float*)(ws + OFF_C);
  float* att2   = (float*)(ws + OFF_ATT2);
  float* gate   = (float*)(ws + OFF_GATE);
  float* alpha  = (float*)(ws + OFF_ALPHA);
  f16*   xcat   = (f16*)(ws + OFF_XCAT);
  int*   wsi    = (int*)(ws + OFF_INT);
  int*   perm   = wsi;
  int*   declen = wsi + 64;
  int*   caps_s = wsi + 128;
  f16*   enc16  = (f16*)(ws + OFF_ENC16);

  const bool full = ws_size >= FULL_BYTES;

  float* out         = (float*)d_out;
  float* out_pred    = out;
  float* out_caps    = out_pred + (size_t)NB * NTD * NV;
  float* out_declen  = out_caps + (size_t)NB * NT_CAP;
  float* out_alphas  = out_declen + NB;
  float* out_sortind = out_alphas + (size_t)NB * NTD * NP;

  k_sort<<<1, 64, 0, stream>>>(caplen, caps, perm, declen, caps_s,
                               out_caps, out_declen, out_sortind);
  k_tconv<<<dim3(16, 64), 256, 0, stream>>>(enc_att_W, eaWt, 2048, 512);
  k_tconv<<<dim3(16, 16), 256, 0, stream>>>(dec_att_W, daWt, 512, 512);
  k_tconv<<<dim3(64, 16), 256, 0, stream>>>(f_beta_W, fbWt, 512, 2048);
  k_tconv<<<dim3(16, 64), 256, 0, stream>>>(init_h_W, ihWt, 2048, 512);
  k_tconv<<<dim3(16, 64), 256, 0, stream>>>(init_c_W, icWt, 2048, 512);
  k_mean<<<dim3(4, 64), 256, 0, stream>>>(enc, perm, mean16);
  if (full) k_enc_cvt<<<dim3(196, 64), 256, 0, stream>>>(enc, perm, enc16);
  k_init_mfma<<<dim3(8, 2), 256, 0, stream>>>(mean16, ihWt, icWt, init_h_b, init_c_b,
                                              h16, cst);
  if (full)
    k_att1_mfma<true><<<dim3(2, 196), 256, 0, stream>>>(enc, enc16, perm, eaWt,
                                                        enc_att_b, att1);
  else
    k_att1_mfma<false><<<dim3(2, 196), 256, 0, stream>>>(enc, enc16, perm, eaWt,
                                                         enc_att_b, att1);
  // fcWt write ALIASES eaWt/ihWt/icWt — must come after k_init/k_att1 (stream order).
  k_tconv<<<dim3(314, 16), 256, 0, stream>>>(fc_W, fcWt, 512, NV);
  k_cvt_wcat<<<2048, 256, 0, stream>>>(W_ih, W_hh, Wcat);

  for (int t = 0; t < NTD; ++t) {
    k_hgemm_mfma<<<40, 256, 0, stream>>>(h16, daWt, dec_att_b, fbWt, f_beta_b,
                                         att2, gate);
    k_attn<<<NB, 256, 0, stream>>>(att1, att2, full_att_W, declen, t, alpha, out_alphas);
    if (full)
      k_awe_x<true><<<dim3(3, 64), 256, 0, stream>>>(enc, enc16, perm, alpha, gate,
                                                     emb, caps_s, h16, t, xcat);
    else
      k_awe_x<false><<<dim3(3, 64), 256, 0, stream>>>(enc, enc16, perm, alpha, gate,
                                                      emb, caps_s, h16, t, xcat);
    k_xlstm_mfma<<<128, 256, 0, stream>>>(xcat, Wcat, b_ih, b_hh, declen, t,
                                          cst, h16, hnew16);
    k_fc_mfma<<<157, 256, 0, stream>>>(hnew16, fcWt, fc_b, declen, t, out_pred);
  }
}

// Round 4
// 2154.052 us; speedup vs baseline: 2.5002x; 1.3057x over previous
//
#include <hip/hip_runtime.h>
#include <cstddef>

// ---------------------------------------------------------------------------
// DecoderWithAttention forward — Round 4.
// Per-step GEMMs are barrier-free: MFMA fragments loaded directly from global
// (A = 64-row activation, L1-hot; B = f16 weight, streamed once from L2/LLC).
// xlstm: Wcat pre-permuted (r=d*4+g), 4-way K-split + one LDS reduce.
// att1: LDS-staged, grid (4,196), NT=8 -> ~3 blocks/CU.
// ---------------------------------------------------------------------------

namespace {

typedef _Float16 f16;
typedef f16 f16x8 __attribute__((ext_vector_type(8)));
typedef f16 f16x4 __attribute__((ext_vector_type(4)));
typedef f16 f16x2 __attribute__((ext_vector_type(2)));
typedef float f32x4 __attribute__((ext_vector_type(4)));

constexpr int NB = 64, NP = 196, NE = 2048, NA = 512, ND = 512, NV = 10000;
constexpr int NT_CAP = 21, NTD = 20;
constexpr int KC = 3072;   // xcat K: 512 emb + 2048 awe + 512 h
constexpr int LDT = 40;    // LDS row stride (f16)

// ---- workspace byte offsets ----
constexpr size_t OFF_ATT1   = 0;           // f16 [12544][512]
constexpr size_t OFF_DAW    = 12845056;    // f16 [512][512]
constexpr size_t OFF_FBW    = 13369344;    // f16 [2048][512]
constexpr size_t OFF_EAW    = 15466496;    // f16 [512][2048]   (preamble only)
constexpr size_t OFF_IHW    = 17563648;    // f16 [512][2048]   (preamble only)
constexpr size_t OFF_ICW    = 19660800;    // f16 [512][2048]   (preamble only)
constexpr size_t OFF_FCW    = 15466496;    // f16 [10048][512]  ALIASES eaW/ihW/icW
constexpr size_t OFF_WCAT   = 25755648;    // f16 [2048][3072]  rows r = d*4+g
constexpr size_t OFF_MEAN16 = 38338560;    // f16 [64][2048]
constexpr size_t OFF_H16    = 38600704;    // f16 [64][512]
constexpr size_t OFF_HNEW16 = 38666240;    // f16 [64][512]
constexpr size_t OFF_C      = 38731776;    // f32 [64][512]
constexpr size_t OFF_ATT2   = 38862848;    // f32 [64][512]
constexpr size_t OFF_GATE   = 38993920;    // f32 [64][2048]
constexpr size_t OFF_ALPHA  = 39518208;    // f32 [64][200]
constexpr size_t OFF_XCAT   = 39569408;    // f16 [64][3072]
constexpr size_t OFF_INT    = 39962624;    // perm/declen/caps (8 KB)
constexpr size_t OFF_BCAT   = 39970816;    // f32 [2048] combined lstm bias, permuted
constexpr size_t OFF_ENC16  = 39979008;    // f16 [64][196][2048] (optional)
constexpr size_t FULL_BYTES = 91359232;

__device__ __forceinline__ float sigmoidf_(float x) { return 1.0f / (1.0f + expf(-x)); }

// stage 64 rows x 32 k of f16 into LDS (256 threads, 16 B each)
__device__ __forceinline__ void stage16(const f16* __restrict__ src, int lda, int k0,
                                        f16* __restrict__ lds, int tid) {
  const int row = tid >> 2, seg = tid & 3;
  *(f16x8*)&lds[row * LDT + seg * 8] =
      *(const f16x8*)&src[(size_t)row * lda + k0 + seg * 8];
}

// convert 8 consecutive fp32 -> 8 f16 at dst
__device__ __forceinline__ void cvt8(const float* __restrict__ p, f16* __restrict__ dst) {
  const float4 a = *(const float4*)p;
  const float4 b = *(const float4*)(p + 4);
  f16x8 v;
  v[0] = (f16)a.x; v[1] = (f16)a.y; v[2] = (f16)a.z; v[3] = (f16)a.w;
  v[4] = (f16)b.x; v[5] = (f16)b.y; v[6] = (f16)b.z; v[7] = (f16)b.w;
  *(f16x8*)dst = v;
}

// Barrier-free wave GEMM: 64m x 16n tile. A [64][K] f16 (m-rows), B rows at
// Brow (n-tile's 16 rows, stride K). Lane (col,quad). acc[mt][0..4].
__device__ __forceinline__ void wave_gemm64(const f16* __restrict__ A,
                                            const f16* __restrict__ Brow, int K,
                                            int kbeg, int kend,
                                            int col, int quad, f32x4* acc) {
  for (int k0 = kbeg; k0 < kend; k0 += 32) {
    const int kk = k0 + quad * 8;
    const f16x8 b = *(const f16x8*)&Brow[(size_t)col * K + kk];
#pragma unroll
    for (int mt = 0; mt < 4; ++mt) {
      const f16x8 a = *(const f16x8*)&A[(size_t)(mt * 16 + col) * K + kk];
      acc[mt] = __builtin_amdgcn_mfma_f32_16x16x32_f16(a, b, acc[mt], 0, 0, 0);
    }
  }
}

// ---------------------------------------------------------------------------
// K1: stable descending argsort + gathered caps/declen/sortind outputs.
// ---------------------------------------------------------------------------
__global__ void k_sort(const int* __restrict__ cap_len, const int* __restrict__ caps,
                       int* __restrict__ perm, int* __restrict__ declen,
                       int* __restrict__ caps_sorted,
                       float* __restrict__ out_caps, float* __restrict__ out_declen,
                       float* __restrict__ out_sortind) {
  __shared__ int cl[NB];
  __shared__ int pr[NB];
  const int i = threadIdx.x;
  int c = cap_len[i];
  if (c < 1) c = 1;
  cl[i] = c;
  __syncthreads();
  int rank = 0;
  for (int j = 0; j < NB; ++j) {
    const int cj = cl[j];
    if (cj > c || (cj == c && j < i)) rank++;
  }
  pr[rank] = i;
  __syncthreads();
  const int src = pr[i];
  perm[i] = src;
  const int dl = cl[src] - 1;
  declen[i] = dl;
  out_declen[i] = (float)dl;
  out_sortind[i] = (float)src;
  for (int j = 0; j < NT_CAP; ++j) {
    const int v = caps[src * NT_CAP + j];
    caps_sorted[i * NT_CAP + j] = v;
    out_caps[i * NT_CAP + j] = (float)v;
  }
}

// ---------------------------------------------------------------------------
// K2: transpose-convert fp32 [K][Nsrc] (K-major) -> f16 [N][K]; zero if n>=Nsrc.
// ---------------------------------------------------------------------------
__global__ __launch_bounds__(256) void k_tconv(const float* __restrict__ src,
                                               f16* __restrict__ dst, int K, int Nsrc) {
  __shared__ float tile[32][33];
  const int n0 = blockIdx.x * 32, k0 = blockIdx.y * 32;
  const int tid = threadIdx.x;
  const int a = tid & 31, q = tid >> 5;
#pragma unroll
  for (int r = 0; r < 4; ++r) {
    const int kl = q * 4 + r;
    tile[a][kl] = (n0 + a < Nsrc) ? src[(size_t)(k0 + kl) * Nsrc + n0 + a] : 0.0f;
  }
  __syncthreads();
#pragma unroll
  for (int r = 0; r < 4; ++r) {
    const int nl = q * 4 + r;
    dst[(size_t)(n0 + nl) * K + k0 + a] = (f16)tile[nl][a];
  }
}

// ---------------------------------------------------------------------------
// K2b: permuted Wcat: row r = d*4+g <-> original n = g*512+d.
//      Wcat2[r][k] = f16(k<2560 ? W_ih[n][k] : W_hh[n][k-2560]);
//      bcat[r] = b_ih[n] + b_hh[n].
// ---------------------------------------------------------------------------
__global__ __launch_bounds__(256) void k_cvt_wcat2(const float* __restrict__ Wih,
                                                   const float* __restrict__ Whh,
                                                   const float* __restrict__ bih,
                                                   const float* __restrict__ bhh,
                                                   f16* __restrict__ Wcat2,
                                                   float* __restrict__ bcat) {
  const int r = blockIdx.x;
  const int d = r >> 2, g = r & 3;
  const int n = g * 512 + d;
  for (int k = threadIdx.x; k < KC; k += 256) {
    const float v = (k < 2560) ? Wih[(size_t)n * 2560 + k] : Whh[(size_t)n * 512 + (k - 2560)];
    Wcat2[(size_t)r * KC + k] = (f16)v;
  }
  if (threadIdx.x == 0) bcat[r] = bih[n] + bhh[n];
}

// ---------------------------------------------------------------------------
// K3: mean over P of sorted encoder rows -> mean16. grid (4, 64).
// ---------------------------------------------------------------------------
__global__ __launch_bounds__(256) void k_mean(const float* __restrict__ enc,
                                              const int* __restrict__ perm,
                                              f16* __restrict__ mean16) {
  const int b = blockIdx.y;
  const int c0 = blockIdx.x * 512 + threadIdx.x * 2;
  const float* base = enc + (size_t)perm[b] * NP * NE + c0;
  float a0 = 0.0f, a1 = 0.0f;
  for (int p = 0; p < NP; ++p) {
    const float2 v = *(const float2*)&base[(size_t)p * NE];
    a0 += v.x; a1 += v.y;
  }
  mean16[(size_t)b * NE + c0] = (f16)(a0 * (1.0f / (float)NP));
  mean16[(size_t)b * NE + c0 + 1] = (f16)(a1 * (1.0f / (float)NP));
}

// ---------------------------------------------------------------------------
// K4 (FULL only): enc16[b][p][c] = f16(enc[perm[b]][p][c]). grid (196, 64).
// ---------------------------------------------------------------------------
__global__ __launch_bounds__(256) void k_enc_cvt(const float* __restrict__ enc,
                                                 const int* __restrict__ perm,
                                                 f16* __restrict__ enc16) {
  const int p = blockIdx.x, b = blockIdx.y;
  const float* src = enc + ((size_t)perm[b] * NP + p) * NE;
  f16* dst = enc16 + ((size_t)b * NP + p) * NE;
  const int i0 = threadIdx.x * 8;
  cvt8(src + i0, dst + i0);
}

// ---------------------------------------------------------------------------
// K5: h0/c0 = tanh(mean @ W + b), barrier-free direct MFMA. grid (16, 2).
// block = 4 waves; wave nt = bx*4+wv handles n-tile (16 cols) x all 64 m.
// ---------------------------------------------------------------------------
__global__ __launch_bounds__(256) void k_init_mfma(const f16* __restrict__ mean16,
                                                   const f16* __restrict__ ihWt,
                                                   const f16* __restrict__ icWt,
                                                   const float* __restrict__ ihb,
                                                   const float* __restrict__ icb,
                                                   f16* __restrict__ h16,
                                                   float* __restrict__ cst) {
  const int which = blockIdx.y;
  const f16* Wt = which ? icWt : ihWt;
  const float* bias = which ? icb : ihb;
  const int tid = threadIdx.x, lane = tid & 63, wv = tid >> 6;
  const int col = lane & 15, quad = lane >> 4;
  const int nt = blockIdx.x * 4 + wv;  // 0..31
  f32x4 acc[4] = {};
  wave_gemm64(mean16, Wt + (size_t)nt * 16 * NE, NE, 0, NE, col, quad, acc);
  const int n = nt * 16 + col;
#pragma unroll
  for (int mt = 0; mt < 4; ++mt) {
#pragma unroll
    for (int rr = 0; rr < 4; ++rr) {
      const int m = mt * 16 + quad * 4 + rr;
      const float v = tanhf(acc[mt][rr] + bias[n]);
      if (which == 0) h16[(size_t)m * ND + n] = (f16)v;
      else            cst[(size_t)m * ND + n] = v;
    }
  }
}

// ---------------------------------------------------------------------------
// K6: att1 = enc @ enc_att_W + b -> f16. grid (4, 196): 64 rows x 128 cols.
// LDS-staged (A reused by 4 waves x 8 n-tiles), 15 KB LDS -> ~3 blocks/CU.
// ---------------------------------------------------------------------------
template <bool E16>
__global__ __launch_bounds__(256) void k_att1_mfma(const float* __restrict__ encf,
                                                   const f16* __restrict__ enc16,
                                                   const int* __restrict__ perm,
                                                   const f16* __restrict__ eaWt,
                                                   const float* __restrict__ eab,
                                                   f16* __restrict__ att1) {
  __shared__ __align__(16) f16 lA[64 * LDT];
  __shared__ __align__(16) f16 lB[128 * LDT];
  __shared__ int rowoff[64];
  const int r0 = blockIdx.y * 64;
  const int n0 = blockIdx.x * 128;
  const int tid = threadIdx.x, lane = tid & 63, wv = tid >> 6;
  const int col = lane & 15, quad = lane >> 4;
  if (!E16) {
    if (tid < 64) {
      const int r = r0 + tid;
      const int b = r / NP, p = r - b * NP;
      rowoff[tid] = (perm[b] * NP + p) * NE;
    }
    __syncthreads();
  }
  f32x4 acc[8] = {};
  for (int k0 = 0; k0 < NE; k0 += 32) {
    if (E16) {
      stage16(enc16 + (size_t)r0 * NE, NE, k0, lA, tid);
    } else {
      const int row = tid >> 2, seg = tid & 3;
      cvt8(encf + (size_t)rowoff[row] + k0 + seg * 8, &lA[row * LDT + seg * 8]);
    }
    {
      const int row0 = tid >> 2, seg = tid & 3;
#pragma unroll
      for (int u = 0; u < 2; ++u) {
        const int row = row0 + 64 * u;
        *(f16x8*)&lB[row * LDT + seg * 8] =
            *(const f16x8*)&eaWt[(size_t)(n0 + row) * NE + k0 + seg * 8];
      }
    }
    __syncthreads();
    const f16x8 a = *(const f16x8*)&lA[(wv * 16 + col) * LDT + quad * 8];
#pragma unroll
    for (int ns = 0; ns < 8; ++ns) {
      const f16x8 b = *(const f16x8*)&lB[(ns * 16 + col) * LDT + quad * 8];
      acc[ns] = __builtin_amdgcn_mfma_f32_16x16x32_f16(a, b, acc[ns], 0, 0, 0);
    }
    __syncthreads();
  }
#pragma unroll
  for (int ns = 0; ns < 8; ++ns) {
    const int n = n0 + ns * 16 + col;
#pragma unroll
    for (int rr = 0; rr < 4; ++rr) {
      const int r = r0 + wv * 16 + quad * 4 + rr;
      att1[(size_t)r * NA + n] = (f16)(acc[ns][rr] + eab[n]);
    }
  }
}

// ---------------------------------------------------------------------------
// K7 (per step): h-GEMM -> att2/gate, barrier-free. 40 blocks x 4 waves;
// wave nt in [0,160): nt<32 -> att2 n-tile, else gate n-tile.
// ---------------------------------------------------------------------------
__global__ __launch_bounds__(256) void k_hgemm_mfma(const f16* __restrict__ h16,
                                                    const f16* __restrict__ daWt,
                                                    const float* __restrict__ dab,
                                                    const f16* __restrict__ fbWt,
                                                    const float* __restrict__ fbb,
                                                    float* __restrict__ att2,
                                                    float* __restrict__ gate) {
  const int tid = threadIdx.x, lane = tid & 63, wv = tid >> 6;
  const int col = lane & 15, quad = lane >> 4;
  const int nt = blockIdx.x * 4 + wv;  // 0..159
  const bool is_att = nt < 32;
  const f16* Brow = is_att ? (daWt + (size_t)nt * 16 * ND)
                           : (fbWt + (size_t)(nt - 32) * 16 * ND);
  f32x4 acc[4] = {};
  wave_gemm64(h16, Brow, ND, 0, ND, col, quad, acc);
  if (is_att) {
    const int n = nt * 16 + col;
#pragma unroll
    for (int mt = 0; mt < 4; ++mt)
#pragma unroll
      for (int rr = 0; rr < 4; ++rr) {
        const int m = mt * 16 + quad * 4 + rr;
        att2[(size_t)m * NA + n] = acc[mt][rr] + dab[n];
      }
  } else {
    const int n = (nt - 32) * 16 + col;
#pragma unroll
    for (int mt = 0; mt < 4; ++mt)
#pragma unroll
      for (int rr = 0; rr < 4; ++rr) {
        const int m = mt * 16 + quad * 4 + rr;
        gate[(size_t)m * NE + n] = sigmoidf_(acc[mt][rr] + fbb[n]);
      }
  }
}

// ---------------------------------------------------------------------------
// K8 (per step): attention logits + softmax. One block per b.
// ---------------------------------------------------------------------------
__global__ __launch_bounds__(256) void k_attn(const f16* __restrict__ att1,
                                              const float* __restrict__ att2,
                                              const float* __restrict__ fullW,
                                              const int* __restrict__ declen, int t,
                                              float* __restrict__ alpha_ws,
                                              float* __restrict__ out_alphas) {
  const int b = blockIdx.x;
  const int tid = threadIdx.x, wv = tid >> 6, lane = tid & 63;
  float a2r[8], fwr[8];
  {
    const float4* A2 = (const float4*)(att2 + (size_t)b * NA + lane * 8);
    const float4* FW = (const float4*)(fullW + lane * 8);
    const float4 q0 = A2[0], q1 = A2[1], w0 = FW[0], w1 = FW[1];
    a2r[0] = q0.x; a2r[1] = q0.y; a2r[2] = q0.z; a2r[3] = q0.w;
    a2r[4] = q1.x; a2r[5] = q1.y; a2r[6] = q1.z; a2r[7] = q1.w;
    fwr[0] = w0.x; fwr[1] = w0.y; fwr[2] = w0.z; fwr[3] = w0.w;
    fwr[4] = w1.x; fwr[5] = w1.y; fwr[6] = w1.z; fwr[7] = w1.w;
  }
  __shared__ float e[200];
  __shared__ float sred[256];
  for (int p = wv; p < NP; p += 4) {
    const f16x8 row = *(const f16x8*)(att1 + ((size_t)b * NP + p) * NA + lane * 8);
    float acc = 0.0f;
#pragma unroll
    for (int j = 0; j < 8; ++j) acc += fmaxf((float)row[j] + a2r[j], 0.0f) * fwr[j];
#pragma unroll
    for (int off = 32; off > 0; off >>= 1) acc += __shfl_down(acc, off, 64);
    if (lane == 0) e[p] = acc;
  }
  __syncthreads();
  sred[tid] = (tid < NP) ? e[tid] : -INFINITY;
  __syncthreads();
  for (int s = 128; s > 0; s >>= 1) {
    if (tid < s) sred[tid] = fmaxf(sred[tid], sred[tid + s]);
    __syncthreads();
  }
  const float m = sred[0];
  __syncthreads();
  const float ex = (tid < NP) ? expf(e[tid] - m) : 0.0f;
  sred[tid] = ex;
  __syncthreads();
  for (int s = 128; s > 0; s >>= 1) {
    if (tid < s) sred[tid] += sred[tid + s];
    __syncthreads();
  }
  const float inv = 1.0f / sred[0];
  if (tid < NP) {
    const float al = ex * inv;
    alpha_ws[(size_t)b * NP + tid] = al;
    const bool act = t < declen[b];
    out_alphas[((size_t)b * NTD + t) * NP + tid] = act ? al : 0.0f;
  }
}

// ---------------------------------------------------------------------------
// K9 (per step): awe + gate + build xcat. grid (3, 64):
//   s<2:  1024-ch slice: xcat[b][512+c] = f16(gate*sum_p alpha*enc)
//   s==2: xcat[b][0:512)=emb[cap], xcat[b][2560:3072)=h16
// ---------------------------------------------------------------------------
template <bool E16>
__global__ __launch_bounds__(256) void k_awe_x(const float* __restrict__ encf,
                                               const f16* __restrict__ enc16,
                                               const int* __restrict__ perm,
                                               const float* __restrict__ alpha_ws,
                                               const float* __restrict__ gate,
                                               const float* __restrict__ emb,
                                               const int* __restrict__ caps_s,
                                               const f16* __restrict__ h16, int t,
                                               f16* __restrict__ xcat) {
  const int s = blockIdx.x, b = blockIdx.y, tid = threadIdx.x;
  if (s == 2) {
    const int cap = caps_s[b * NT_CAP + t];
    const int i0 = tid * 2;
    const float2 v = *(const float2*)(emb + (size_t)cap * 512 + i0);
    f16x2 ev; ev[0] = (f16)v.x; ev[1] = (f16)v.y;
    *(f16x2*)&xcat[(size_t)b * KC + i0] = ev;
    *(f16x2*)&xcat[(size_t)b * KC + 2560 + i0] = *(const f16x2*)&h16[(size_t)b * ND + i0];
    return;
  }
  __shared__ float al[NP];
  if (tid < NP) al[tid] = alpha_ws[(size_t)b * NP + tid];
  __syncthreads();
  const int c = s * 1024 + tid * 4;
  float a0 = 0.0f, a1 = 0.0f, a2 = 0.0f, a3 = 0.0f;
  if (E16) {
    const f16* base = enc16 + (size_t)b * NP * NE + c;
    for (int p = 0; p < NP; ++p) {
      const f16x4 v = *(const f16x4*)&base[(size_t)p * NE];
      const float ap = al[p];
      a0 += ap * (float)v[0]; a1 += ap * (float)v[1];
      a2 += ap * (float)v[2]; a3 += ap * (float)v[3];
    }
  } else {
    const float* base = encf + (size_t)perm[b] * NP * NE + c;
    for (int p = 0; p < NP; ++p) {
      const float4 v = *(const float4*)&base[(size_t)p * NE];
      const float ap = al[p];
      a0 += ap * v.x; a1 += ap * v.y; a2 += ap * v.z; a3 += ap * v.w;
    }
  }
  const float4 g = *(const float4*)&gate[(size_t)b * NE + c];
  f16x4 o;
  o[0] = (f16)(a0 * g.x); o[1] = (f16)(a1 * g.y);
  o[2] = (f16)(a2 * g.z); o[3] = (f16)(a3 * g.w);
  *(f16x4*)&xcat[(size_t)b * KC + 512 + c] = o;
}

// ---------------------------------------------------------------------------
// K10 (per step): gates = xcat @ Wcat2^T (rows r=d*4+g), fused LSTM cell.
// 128 blocks; block = n-tile nt (16 rows = 4 d x 4 gates) x 64 m.
// 4 waves K-split 3072/4=768 each; LDS reduce; per-thread cell epilogue.
// ---------------------------------------------------------------------------
__global__ __launch_bounds__(256) void k_xlstm_mfma(const f16* __restrict__ xcat,
                                                    const f16* __restrict__ Wcat2,
                                                    const float* __restrict__ bcat,
                                                    const int* __restrict__ declen, int t,
                                                    float* __restrict__ cst,
                                                    f16* __restrict__ h16,
                                                    f16* __restrict__ hnew16) {
  __shared__ float R[4 * 64 * 16];
  const int nt = blockIdx.x;
  const int tid = threadIdx.x, lane = tid & 63, wv = tid >> 6;
  const int col = lane & 15, quad = lane >> 4;
  f32x4 acc[4] = {};
  wave_gemm64(xcat, Wcat2 + (size_t)nt * 16 * KC, KC, wv * 768, (wv + 1) * 768,
              col, quad, acc);
#pragma unroll
  for (int mt = 0; mt < 4; ++mt)
#pragma unroll
    for (int rr = 0; rr < 4; ++rr)
      R[(wv * 64 + lane) * 16 + mt * 4 + rr] = acc[mt][rr];
  __syncthreads();
  {
    const int j0 = tid * 4;
#pragma unroll
    for (int j = 0; j < 4; ++j) {
      const int e = j0 + j;
      R[e] = R[e] + R[1024 + e] + R[2048 + e] + R[3072 + e];
    }
  }
  __syncthreads();
  // epilogue: thread tid -> m = tid>>2, d_local = tid&3
  const int m = tid >> 2, dl = tid & 3;
  const int mt = m >> 4, qd = (m >> 2) & 3, rr = m & 3;
  float g4[4];
#pragma unroll
  for (int g = 0; g < 4; ++g) {
    const int cv = dl * 4 + g;                 // local n (row in tile)
    g4[g] = R[(qd * 16 + cv) * 16 + mt * 4 + rr] + bcat[nt * 16 + cv];
  }
  const int d = nt * 4 + dl;
  const float iv = sigmoidf_(g4[0]);
  const float fv = sigmoidf_(g4[1]);
  const float gv = tanhf(g4[2]);
  const float ov = sigmoidf_(g4[3]);
  const float cold = cst[(size_t)m * ND + d];
  const float cn = fv * cold + iv * gv;
  const float hn = ov * tanhf(cn);
  hnew16[(size_t)m * ND + d] = (f16)hn;
  if (t < declen[m]) {
    cst[(size_t)m * ND + d] = cn;
    h16[(size_t)m * ND + d] = (f16)hn;
  }
}

// ---------------------------------------------------------------------------
// K11 (per step): preds = hnew16 @ fcWt^T + fc_b (masked), barrier-free.
// 157 blocks x 4 waves; wave nt in [0,628).
// ---------------------------------------------------------------------------
__global__ __launch_bounds__(256) void k_fc_mfma(const f16* __restrict__ hnew16,
                                                 const f16* __restrict__ fcWt,
                                                 const float* __restrict__ fcb,
                                                 const int* __restrict__ declen, int t,
                                                 float* __restrict__ out_pred) {
  const int tid = threadIdx.x, lane = tid & 63, wv = tid >> 6;
  const int col = lane & 15, quad = lane >> 4;
  const int nt = blockIdx.x * 4 + wv;  // 0..627
  f32x4 acc[4] = {};
  wave_gemm64(hnew16, fcWt + (size_t)nt * 16 * ND, ND, 0, ND, col, quad, acc);
  const int n = nt * 16 + col;
  if (n < NV) {
    const float bv = fcb[n];
#pragma unroll
    for (int mt = 0; mt < 4; ++mt)
#pragma unroll
      for (int rr = 0; rr < 4; ++rr) {
        const int m = mt * 16 + quad * 4 + rr;
        const bool act = t < declen[m];
        out_pred[((size_t)m * NTD + t) * NV + n] = act ? (acc[mt][rr] + bv) : 0.0f;
      }
  }
}

}  // namespace

extern "C" void kernel_launch(void* const* d_in, const int* in_sizes, int n_in,
                              void* d_out, int out_size, void* d_ws, size_t ws_size,
                              hipStream_t stream) {
  const float* enc        = (const float*)d_in[0];
  const int*   caps       = (const int*)d_in[1];
  const int*   caplen     = (const int*)d_in[2];
  const float* emb        = (const float*)d_in[3];
  const float* enc_att_W  = (const float*)d_in[4];
  const float* enc_att_b  = (const float*)d_in[5];
  const float* dec_att_W  = (const float*)d_in[6];
  const float* dec_att_b  = (const float*)d_in[7];
  const float* full_att_W = (const float*)d_in[8];
  // d_in[9] full_att_b: shift-invariant under softmax, unused.
  const float* init_h_W   = (const float*)d_in[10];
  const float* init_h_b   = (const float*)d_in[11];
  const float* init_c_W   = (const float*)d_in[12];
  const float* init_c_b   = (const float*)d_in[13];
  const float* f_beta_W   = (const float*)d_in[14];
  const float* f_beta_b   = (const float*)d_in[15];
  const float* W_ih       = (const float*)d_in[16];
  const float* b_ih       = (const float*)d_in[17];
  const float* W_hh       = (const float*)d_in[18];
  const float* b_hh       = (const float*)d_in[19];
  const float* fc_W       = (const float*)d_in[20];
  const float* fc_b       = (const float*)d_in[21];

  char* ws = (char*)d_ws;
  f16*   att1   = (f16*)(ws + OFF_ATT1);
  f16*   daWt   = (f16*)(ws + OFF_DAW);
  f16*   fbWt   = (f16*)(ws + OFF_FBW);
  f16*   eaWt   = (f16*)(ws + OFF_EAW);
  f16*   ihWt   = (f16*)(ws + OFF_IHW);
  f16*   icWt   = (f16*)(ws + OFF_ICW);
  f16*   fcWt   = (f16*)(ws + OFF_FCW);   // aliases eaWt/ihWt/icWt (written after)
  f16*   Wcat2  = (f16*)(ws + OFF_WCAT);
  f16*   mean16 = (f16*)(ws + OFF_MEAN16);
  f16*   h16    = (f16*)(ws + OFF_H16);
  f16*   hnew16 = (f16*)(ws + OFF_HNEW16);
  float* cst    = (float*)(ws + OFF_C);
  float* att2   = (float*)(ws + OFF_ATT2);
  float* gate   = (float*)(ws + OFF_GATE);
  float* alpha  = (float*)(ws + OFF_ALPHA);
  f16*   xcat   = (f16*)(ws + OFF_XCAT);
  int*   wsi    = (int*)(ws + OFF_INT);
  int*   perm   = wsi;
  int*   declen = wsi + 64;
  int*   caps_s = wsi + 128;
  float* bcat   = (float*)(ws + OFF_BCAT);
  f16*   enc16  = (f16*)(ws + OFF_ENC16);

  const bool full = ws_size >= FULL_BYTES;

  float* out         = (float*)d_out;
  float* out_pred    = out;
  float* out_caps    = out_pred + (size_t)NB * NTD * NV;
  float* out_declen  = out_caps + (size_t)NB * NT_CAP;
  float* out_alphas  = out_declen + NB;
  float* out_sortind = out_alphas + (size_t)NB * NTD * NP;

  k_sort<<<1, 64, 0, stream>>>(caplen, caps, perm, declen, caps_s,
                               out_caps, out_declen, out_sortind);
  k_tconv<<<dim3(16, 64), 256, 0, stream>>>(enc_att_W, eaWt, 2048, 512);
  k_tconv<<<dim3(16, 16), 256, 0, stream>>>(dec_att_W, daWt, 512, 512);
  k_tconv<<<dim3(64, 16), 256, 0, stream>>>(f_beta_W, fbWt, 512, 2048);
  k_tconv<<<dim3(16, 64), 256, 0, stream>>>(init_h_W, ihWt, 2048, 512);
  k_tconv<<<dim3(16, 64), 256, 0, stream>>>(init_c_W, icWt, 2048, 512);
  k_mean<<<dim3(4, 64), 256, 0, stream>>>(enc, perm, mean16);
  if (full) k_enc_cvt<<<dim3(196, 64), 256, 0, stream>>>(enc, perm, enc16);
  k_init_mfma<<<dim3(16, 2), 256, 0, stream>>>(mean16, ihWt, icWt, init_h_b, init_c_b,
                                               h16, cst);
  if (full)
    k_att1_mfma<true><<<dim3(4, 196), 256, 0, stream>>>(enc, enc16, perm, eaWt,
                                                        enc_att_b, att1);
  else
    k_att1_mfma<false><<<dim3(4, 196), 256, 0, stream>>>(enc, enc16, perm, eaWt,
                                                         enc_att_b, att1);
  // fcWt write ALIASES eaWt/ihWt/icWt — must come after k_init/k_att1 (stream order).
  k_tconv<<<dim3(314, 16), 256, 0, stream>>>(fc_W, fcWt, 512, NV);
  k_cvt_wcat2<<<2048, 256, 0, stream>>>(W_ih, W_hh, b_ih, b_hh, Wcat2, bcat);

  for (int t = 0; t < NTD; ++t) {
    k_hgemm_mfma<<<40, 256, 0, stream>>>(h16, daWt, dec_att_b, fbWt, f_beta_b,
                                         att2, gate);
    k_attn<<<NB, 256, 0, stream>>>(att1, att2, full_att_W, declen, t, alpha, out_alphas);
    if (full)
      k_awe_x<true><<<dim3(3, 64), 256, 0, stream>>>(enc, enc16, perm, alpha, gate,
                                                     emb, caps_s, h16, t, xcat);
    else
      k_awe_x<false><<<dim3(3, 64), 256, 0, stream>>>(enc, enc16, perm, alpha, gate,
                                                      emb, caps_s, h16, t, xcat);
    k_xlstm_mfma<<<128, 256, 0, stream>>>(xcat, Wcat2, bcat, declen, t,
                                          cst, h16, hnew16);
    k_fc_mfma<<<157, 256, 0, stream>>>(hnew16, fcWt, fc_b, declen, t, out_pred);
  }
}